// Round 3
// baseline (711.329 us; speedup 1.0000x reference)
//
#include <hip/hip_runtime.h>
#include <hip/hip_bf16.h>

// Problem dims (fixed): T=1024, B=32, DIN=256, H=256, AA=21, L=2
#define T_DIM 1024
#define B_DIM 32
#define DIN_DIM 256
#define H_DIM 256
#define AA_DIM 21
#define M_ROWS (B_DIM * T_DIM)   // 32768 rows, row index = b*T + t everywhere

typedef __attribute__((ext_vector_type(8))) short bf16x8;   // 8 bf16 = 4 VGPRs
typedef __attribute__((ext_vector_type(4))) float f32x4;

typedef __attribute__((address_space(3))) void lds_void;
typedef const __attribute__((address_space(1))) void glb_void;

__device__ __forceinline__ void gload_lds16(const void* g, void* l) {
    // global gather (per-lane addr) -> LDS at (wave-uniform base + lane*16)
    __builtin_amdgcn_global_load_lds((glb_void*)g, (lds_void*)l, 16, 0, 0);
}

__device__ __forceinline__ float b2f(unsigned short v) {
    unsigned u = ((unsigned)v) << 16;
    float f;
    __builtin_memcpy(&f, &u, 4);
    return f;
}

// ---------------------------------------------------------------------------
// f32 -> bf16 convert
__global__ __launch_bounds__(256) void cvt_bf16(const float* __restrict__ s,
                                                __hip_bfloat16* __restrict__ d, int n) {
    int i = blockIdx.x * 256 + threadIdx.x;
    if (i < n) d[i] = __float2bfloat16(s[i]);
}

// SRU weight: f32 (K, 2, 4, H) -> bf16 (N=2048, K) transposed with INTERLEAVED
// row order: n = dir*1024 + h*4 + k  (GEMM output U then has the 4 gates of one
// (dir,h) adjacent -> scan does ONE 8B load per timestep)
__global__ __launch_bounds__(256) void cvt_w_sru(const float* __restrict__ s,
                                                 __hip_bfloat16* __restrict__ d,
                                                 int K) {
    int i = blockIdx.x * 256 + threadIdx.x;
    if (i >= K * 2048) return;
    // input flat: ((kk*2 + dir)*4 + k)*H + h
    int kk  = i >> 11;
    int rem = i & 2047;
    int dir = rem >> 10;
    int k   = (rem >> 8) & 3;
    int h   = rem & 255;
    int n   = dir * 1024 + h * 4 + k;
    d[(long)n * K + kk] = __float2bfloat16(s[i]);
}

// ---------------------------------------------------------------------------
// bf16 GEMM: C(M,N) = A(M,K) * Bt(N,K)^T  [+ bias], C stored bf16.
// 128x128 tile, BK=32, k-major LDS staging (bank-conflict-free fragment reads),
// LDS-staged coalesced epilogue (no C read-modify-write).
__global__ __launch_bounds__(256) void gemm_bf16(
    const __hip_bfloat16* __restrict__ A,
    const __hip_bfloat16* __restrict__ Bt,
    const float* __restrict__ bias,   // len N or nullptr
    __hip_bfloat16* __restrict__ C,
    int M, int N, int K)
{
    // staging: A tile bytes [0,8192): addr = q*2048 + row*16 (q = k-octet 0..3)
    //          B tile bytes [8192,16384): same layout
    // epilogue: reused as [128 rows][stride 144B] bf16 C-tile (18432 B)
    __shared__ __align__(16) char smb[18432];
    __hip_bfloat16* smA = (__hip_bfloat16*)smb;          // element (row, q*8+e) at q*1024 + row*8 + e
    __hip_bfloat16* smB = (__hip_bfloat16*)(smb + 8192);

    const int tid  = threadIdx.x;
    const int lane = tid & 63;
    const int wave = tid >> 6;
    const int wm = wave & 1;
    const int wn = wave >> 1;
    const long m0 = (long)blockIdx.x * 128;
    const long n0 = (long)blockIdx.y * 128;

    f32x4 acc[4][4] = {};

    const int fr    = lane & 15;
    const int qsel  = lane >> 4;          // k-octet 0..3
    const int q1024 = qsel * 1024;        // bf16 units

    for (int kb = 0; kb < K; kb += 32) {
        __syncthreads();
#pragma unroll
        for (int i = 0; i < 4; ++i) {
            const int cid  = wave * 4 + i;     // 0..15
            const int sub  = cid & 7;
            const int q    = sub >> 1;
            const int half = sub & 1;
            const long grow = half * 64 + lane;
            const __hip_bfloat16* gp = (cid < 8)
                ? A  + (m0 + grow) * (long)K + kb + q * 8
                : Bt + (n0 + grow) * (long)K + kb + q * 8;
            void* lp = smb + (cid < 8 ? 0 : 8192) + q * 2048 + half * 1024;
            gload_lds16(gp, lp);
        }
        __syncthreads();   // drains vmcnt(0): staged data visible

        bf16x8 af[4], bfv[4];
#pragma unroll
        for (int i = 0; i < 4; ++i) {
            af[i]  = *(const bf16x8*)(smA + q1024 + (wm * 64 + i * 16 + fr) * 8);
            bfv[i] = *(const bf16x8*)(smB + q1024 + (wn * 64 + i * 16 + fr) * 8);
        }
#pragma unroll
        for (int i = 0; i < 4; ++i)
#pragma unroll
            for (int j = 0; j < 4; ++j)
                acc[i][j] = __builtin_amdgcn_mfma_f32_16x16x32_bf16(
                    af[i], bfv[j], acc[i][j], 0, 0, 0);
    }

    // ---- epilogue: C/D layout col=lane&15, row=(lane>>4)*4+reg ----
    const int col_l = lane & 15;
    const int row_l = (lane >> 4) * 4;
    __hip_bfloat16* smC = (__hip_bfloat16*)smb;   // stride 72 bf16 = 144 B
#pragma unroll
    for (int p = 0; p < 2; ++p) {
        __syncthreads();   // K-loop LDS reads / previous pass reads done
        if (wn == p) {
#pragma unroll
            for (int j = 0; j < 4; ++j) {
                const long gc = n0 + p * 64 + j * 16 + col_l;
                const float bv = bias ? bias[gc] : 0.0f;
#pragma unroll
                for (int i = 0; i < 4; ++i)
#pragma unroll
                    for (int r = 0; r < 4; ++r)
                        smC[(wm * 64 + i * 16 + row_l + r) * 72 + j * 16 + col_l] =
                            __float2bfloat16(acc[i][j][r] + bv);
            }
        }
        __syncthreads();
        const int orow = tid >> 3;          // 0..31
        const int ocs  = (tid & 7) * 8;     // col start, bf16 units
#pragma unroll
        for (int rnd = 0; rnd < 4; ++rnd) {
            const int rr = rnd * 32 + orow;
            bf16x8 v = *(const bf16x8*)(smC + rr * 72 + ocs);
            *(bf16x8*)(C + (m0 + rr) * (long)N + n0 + p * 64 + ocs) = v;
        }
    }
}

// ---------------------------------------------------------------------------
// SRU scan, one thread per (dir, b, h) recurrence; 16384 threads = 1 wave/CU.
// U layout INTERLEAVED: col = dir*1024 + h*4 + k -> one ushort4 (8B) load per
// step. Depth-16 register prefetch ring -> throughput-bound.
#define SCAN_PF 16
__global__ __launch_bounds__(64) void sru_scan(
    const __hip_bfloat16* __restrict__ U,
    const float* __restrict__ wc,    // (2,2,H): [dir][vf,vr][h]
    const float* __restrict__ bias,  // (2,2,H): [dir][bf,br][h]
    __hip_bfloat16* __restrict__ hout)
{
    const int id  = blockIdx.x * 64 + threadIdx.x;  // 0..16383
    const int dir = id >> 13;
    const int rem = id & 8191;
    const int b   = rem >> 8;
    const int h   = rem & 255;

    const float vf = wc[(dir * 2 + 0) * H_DIM + h];
    const float vr = wc[(dir * 2 + 1) * H_DIM + h];
    const float bf = bias[(dir * 2 + 0) * H_DIM + h];
    const float br = bias[(dir * 2 + 1) * H_DIM + h];

    const long row0  = (long)b * T_DIM + (dir ? (T_DIM - 1) : 0);
    const long rstep = dir ? -2048 : 2048;
    const ushort4* p = (const ushort4*)(U + row0 * 2048 + dir * 1024 + (h << 2));
    const long pstep = rstep / 4;

    __hip_bfloat16* ho = hout + row0 * 512 + dir * 256 + h;
    const long hstep = dir ? -512 : 512;

    ushort4 buf[SCAN_PF];
#pragma unroll
    for (int j = 0; j < SCAN_PF; ++j) buf[j] = p[j * pstep];

    float c = 0.0f;
    for (int s0 = 0; s0 < T_DIM; s0 += SCAN_PF) {
#pragma unroll
        for (int j = 0; j < SCAN_PF; ++j) {
            const ushort4 u = buf[j];
            const int sp = s0 + j + SCAN_PF;
            if (sp < T_DIM) buf[j] = p[(long)sp * pstep];
            const float u0 = b2f(u.x);   // candidate
            const float u1 = b2f(u.y);   // forget
            const float u2 = b2f(u.z);   // reset
            const float u3 = b2f(u.w);   // highway
            const float f  = 1.0f / (1.0f + __expf(-(u1 + vf * c + bf)));
            const float c2 = f * (c - u0) + u0;
            const float r  = 1.0f / (1.0f + __expf(-(u2 + vr * c + br)));  // OLD c
            const float hv = r * (c2 - u3) + u3;
            c = c2;
            ho[(long)(s0 + j) * hstep] = __float2bfloat16(hv);
        }
    }
}

// ---------------------------------------------------------------------------
// logits (N=21, K=256) + log_softmax, one thread per row.
__global__ __launch_bounds__(256) void logits_lsm(
    const __hip_bfloat16* __restrict__ fc,   // (M_ROWS, 256) bf16
    const float* __restrict__ lpw,           // (21, 256) f32
    const float* __restrict__ lpb,           // (21,) f32
    float* __restrict__ out, int rows)
{
    const int row = blockIdx.x * 256 + threadIdx.x;
    if (row >= rows) return;
    float acc[AA_DIM];
#pragma unroll
    for (int a = 0; a < AA_DIM; ++a) acc[a] = lpb[a];
    const __hip_bfloat16* hr = fc + (long)row * H_DIM;
    for (int k = 0; k < H_DIM; k += 8) {
        bf16x8 raw = *(const bf16x8*)(hr + k);
#pragma unroll
        for (int j = 0; j < 8; ++j) {
            const float hvj = b2f((unsigned short)raw[j]);
#pragma unroll
            for (int a = 0; a < AA_DIM; ++a)
                acc[a] += hvj * lpw[a * H_DIM + k + j];
        }
    }
    float m = acc[0];
#pragma unroll
    for (int a = 1; a < AA_DIM; ++a) m = fmaxf(m, acc[a]);
    float s = 0.0f;
#pragma unroll
    for (int a = 0; a < AA_DIM; ++a) s += __expf(acc[a] - m);
    const float lse = __logf(s) + m;
#pragma unroll
    for (int a = 0; a < AA_DIM; ++a) out[(long)row * AA_DIM + a] = acc[a] - lse;
}

// ---------------------------------------------------------------------------
extern "C" void kernel_launch(void* const* d_in, const int* in_sizes, int n_in,
                              void* d_out, int out_size, void* d_ws, size_t ws_size,
                              hipStream_t stream)
{
    const float* x     = (const float*)d_in[0];
    const float* w_l0  = (const float*)d_in[2];
    const float* wc_l0 = (const float*)d_in[3];
    const float* b_l0  = (const float*)d_in[4];
    const float* w_l1  = (const float*)d_in[5];
    const float* wc_l1 = (const float*)d_in[6];
    const float* b_l1  = (const float*)d_in[7];
    const float* fc1_w = (const float*)d_in[8];
    const float* fc1_b = (const float*)d_in[9];
    const float* lp_w  = (const float*)d_in[10];
    const float* lp_b  = (const float*)d_in[11];
    float* out = (float*)d_out;

    char* ws = (char*)d_ws;
    __hip_bfloat16* U      = (__hip_bfloat16*)(ws);              // 134,217,728 B
    __hip_bfloat16* h0b    = (__hip_bfloat16*)(ws + 134217728);  //  33,554,432
    __hip_bfloat16* h1b    = (__hip_bfloat16*)(ws + 167772160);  //  33,554,432
    __hip_bfloat16* xb     = (__hip_bfloat16*)(ws + 201326592);  //  16,777,216
    __hip_bfloat16* fcob   = xb;                                 //  alias after GEMM0
    __hip_bfloat16* w0t    = (__hip_bfloat16*)(ws + 218103808);  //  (2048,256)
    __hip_bfloat16* w1t    = (__hip_bfloat16*)(ws + 219152384);  //  (2048,512)
    __hip_bfloat16* fc1wb  = (__hip_bfloat16*)(ws + 221249536);  //  (256,512)

    cvt_bf16<<<(M_ROWS * DIN_DIM + 255) / 256, 256, 0, stream>>>(x, xb, M_ROWS * DIN_DIM);
    cvt_w_sru<<<(DIN_DIM * 2048 + 255) / 256, 256, 0, stream>>>(w_l0, w0t, DIN_DIM);
    cvt_w_sru<<<(512 * 2048 + 255) / 256, 256, 0, stream>>>(w_l1, w1t, 512);
    cvt_bf16<<<(H_DIM * 512 + 255) / 256, 256, 0, stream>>>(fc1_w, fc1wb, H_DIM * 512);

    gemm_bf16<<<dim3(M_ROWS / 128, 2048 / 128), 256, 0, stream>>>(
        xb, w0t, nullptr, U, M_ROWS, 2048, DIN_DIM);
    sru_scan<<<256, 64, 0, stream>>>(U, wc_l0, b_l0, h0b);
    gemm_bf16<<<dim3(M_ROWS / 128, 2048 / 128), 256, 0, stream>>>(
        h0b, w1t, nullptr, U, M_ROWS, 2048, 512);
    sru_scan<<<256, 64, 0, stream>>>(U, wc_l1, b_l1, h1b);
    gemm_bf16<<<dim3(M_ROWS / 128, 256 / 128), 256, 0, stream>>>(
        h1b, fc1wb, fc1_b, fcob, M_ROWS, 256, 512);
    logits_lsm<<<M_ROWS / 256, 256, 0, stream>>>(fcob, lp_w, lp_b, out, M_ROWS);
}

// Round 4
// 609.316 us; speedup vs baseline: 1.1674x; 1.1674x over previous
//
#include <hip/hip_runtime.h>
#include <hip/hip_bf16.h>

// Problem dims (fixed): T=1024, B=32, DIN=256, H=256, AA=21, L=2
#define T_DIM 1024
#define B_DIM 32
#define DIN_DIM 256
#define H_DIM 256
#define AA_DIM 21
#define M_ROWS (B_DIM * T_DIM)   // 32768 rows, row index = b*T + t everywhere

typedef __attribute__((ext_vector_type(8))) short bf16x8;   // 8 bf16 = 4 VGPRs
typedef __attribute__((ext_vector_type(4))) float f32x4;

typedef __attribute__((address_space(3))) void lds_void;
typedef const __attribute__((address_space(1))) void glb_void;

__device__ __forceinline__ void gload_lds16(const void* g, void* l) {
    // global gather (per-lane addr) -> LDS at (wave-uniform base + lane*16)
    __builtin_amdgcn_global_load_lds((glb_void*)g, (lds_void*)l, 16, 0, 0);
}

__device__ __forceinline__ float b2f(unsigned short v) {
    unsigned u = ((unsigned)v) << 16;
    float f;
    __builtin_memcpy(&f, &u, 4);
    return f;
}

// ---------------------------------------------------------------------------
// f32 -> bf16 convert
__global__ __launch_bounds__(256) void cvt_bf16(const float* __restrict__ s,
                                                __hip_bfloat16* __restrict__ d, int n) {
    int i = blockIdx.x * 256 + threadIdx.x;
    if (i < n) d[i] = __float2bfloat16(s[i]);
}

// SRU weight: f32 (K, 2, 4, H) -> bf16 (N=2048, K) transposed with INTERLEAVED
// row order: n = dir*1024 + h*4 + k  (GEMM output U then has the 4 gates of one
// (dir,h) adjacent -> scan does ONE 8B load per timestep)
__global__ __launch_bounds__(256) void cvt_w_sru(const float* __restrict__ s,
                                                 __hip_bfloat16* __restrict__ d,
                                                 int K) {
    int i = blockIdx.x * 256 + threadIdx.x;
    if (i >= K * 2048) return;
    // input flat: ((kk*2 + dir)*4 + k)*H + h
    int kk  = i >> 11;
    int rem = i & 2047;
    int dir = rem >> 10;
    int k   = (rem >> 8) & 3;
    int h   = rem & 255;
    int n   = dir * 1024 + h * 4 + k;
    d[(long)n * K + kk] = __float2bfloat16(s[i]);
}

// ---------------------------------------------------------------------------
// bf16 GEMM: C(M,N) = A(M,K) * Bt(N,K)^T  [+ bias], C stored bf16.
// 128x128 tile, BK=32. Staging: row-major LDS tile (coalesced 16-rows x 64B
// per global_load_lds) with XOR k-quad swizzle: LDS slot (row, q) holds global
// k-quad q ^ ((row>>1)&3). Fragment ds_read_b128s then spread over all 8
// bank-quads per 8-lane issue group -> conflict-free AND coalesced.
// Epilogue: LDS-staged coalesced C store (no read-modify-write).
__global__ __launch_bounds__(256) void gemm_bf16(
    const __hip_bfloat16* __restrict__ A,
    const __hip_bfloat16* __restrict__ Bt,
    const float* __restrict__ bias,   // len N or nullptr
    __hip_bfloat16* __restrict__ C,
    int M, int N, int K)
{
    // A tile bytes [0,8192): addr = row*64 + slot_q*16; B tile [8192,16384)
    // epilogue reuse: [128 rows][stride 144B] bf16 C-tile (18432 B)
    __shared__ __align__(16) char smb[18432];

    const int tid  = threadIdx.x;
    const int lane = tid & 63;
    const int wave = tid >> 6;
    const int wm = wave & 1;
    const int wn = wave >> 1;
    const long m0 = (long)blockIdx.x * 128;
    const long n0 = (long)blockIdx.y * 128;

    f32x4 acc[4][4] = {};

    // staging lane mapping
    const int ldrow = lane >> 2;                    // 0..15 row within 16-row chunk
    const int ldq   = lane & 3;                     // LDS k-quad slot
    const int gq    = ldq ^ ((ldrow >> 1) & 3);     // global k-quad to fetch
    const int gkoff = gq * 8;                       // element offset in k

    // fragment read mapping
    const int fr = lane & 15;
    const int kq = lane >> 4;
    const int sw = (kq ^ ((fr >> 1) & 3)) * 16;     // swizzled byte offset in row

    for (int kb = 0; kb < K; kb += 32) {
        __syncthreads();
#pragma unroll
        for (int i = 0; i < 2; ++i) {
            const int chunk = wave * 2 + i;         // 0..7 -> rows chunk*16..+15
            const long row = chunk * 16 + ldrow;
            gload_lds16(A  + (m0 + row) * (long)K + kb + gkoff, smb + chunk * 1024);
            gload_lds16(Bt + (n0 + row) * (long)K + kb + gkoff, smb + 8192 + chunk * 1024);
        }
        __syncthreads();   // drains vmcnt(0): staged data visible

        bf16x8 af[4], bfv[4];
#pragma unroll
        for (int i = 0; i < 4; ++i) {
            af[i]  = *(const bf16x8*)(smb + (wm * 64 + i * 16 + fr) * 64 + sw);
            bfv[i] = *(const bf16x8*)(smb + 8192 + (wn * 64 + i * 16 + fr) * 64 + sw);
        }
#pragma unroll
        for (int i = 0; i < 4; ++i)
#pragma unroll
            for (int j = 0; j < 4; ++j)
                acc[i][j] = __builtin_amdgcn_mfma_f32_16x16x32_bf16(
                    af[i], bfv[j], acc[i][j], 0, 0, 0);
    }

    // ---- epilogue: C/D layout col=lane&15, row=(lane>>4)*4+reg ----
    const int col_l = lane & 15;
    const int row_l = (lane >> 4) * 4;
    __hip_bfloat16* smC = (__hip_bfloat16*)smb;   // stride 72 bf16 = 144 B
#pragma unroll
    for (int p = 0; p < 2; ++p) {
        __syncthreads();   // prior LDS reads done
        if (wn == p) {
#pragma unroll
            for (int j = 0; j < 4; ++j) {
                const long gc = n0 + p * 64 + j * 16 + col_l;
                const float bv = bias ? bias[gc] : 0.0f;
#pragma unroll
                for (int i = 0; i < 4; ++i)
#pragma unroll
                    for (int r = 0; r < 4; ++r)
                        smC[(wm * 64 + i * 16 + row_l + r) * 72 + j * 16 + col_l] =
                            __float2bfloat16(acc[i][j][r] + bv);
            }
        }
        __syncthreads();
        const int orow = tid >> 3;          // 0..31
        const int ocs  = (tid & 7) * 8;     // col start, bf16 units
#pragma unroll
        for (int rnd = 0; rnd < 4; ++rnd) {
            const int rr = rnd * 32 + orow;
            bf16x8 v = *(const bf16x8*)(smC + rr * 72 + ocs);
            *(bf16x8*)(C + (m0 + rr) * (long)N + n0 + p * 64 + ocs) = v;
        }
    }
}

// ---------------------------------------------------------------------------
// SRU scan, one thread per (dir, b, h) recurrence; 16384 threads = 1 wave/CU.
// U layout INTERLEAVED: col = dir*1024 + h*4 + k -> one ushort4 (8B) load per
// step. Depth-32 register prefetch ring (16 KB in flight per CU).
#define SCAN_PF 32
__global__ __launch_bounds__(64) void sru_scan(
    const __hip_bfloat16* __restrict__ U,
    const float* __restrict__ wc,    // (2,2,H): [dir][vf,vr][h]
    const float* __restrict__ bias,  // (2,2,H): [dir][bf,br][h]
    __hip_bfloat16* __restrict__ hout)
{
    const int id  = blockIdx.x * 64 + threadIdx.x;  // 0..16383
    const int dir = id >> 13;
    const int rem = id & 8191;
    const int b   = rem >> 8;
    const int h   = rem & 255;

    const float vf = wc[(dir * 2 + 0) * H_DIM + h];
    const float vr = wc[(dir * 2 + 1) * H_DIM + h];
    const float bf = bias[(dir * 2 + 0) * H_DIM + h];
    const float br = bias[(dir * 2 + 1) * H_DIM + h];

    const long row0  = (long)b * T_DIM + (dir ? (T_DIM - 1) : 0);
    const long rstep = dir ? -2048 : 2048;
    const ushort4* p = (const ushort4*)(U + row0 * 2048 + dir * 1024 + (h << 2));
    const long pstep = rstep / 4;

    __hip_bfloat16* ho = hout + row0 * 512 + dir * 256 + h;
    const long hstep = dir ? -512 : 512;

    ushort4 buf[SCAN_PF];
#pragma unroll
    for (int j = 0; j < SCAN_PF; ++j) buf[j] = p[j * pstep];

    float c = 0.0f;
    for (int s0 = 0; s0 < T_DIM; s0 += SCAN_PF) {
#pragma unroll
        for (int j = 0; j < SCAN_PF; ++j) {
            const ushort4 u = buf[j];
            const int sp = s0 + j + SCAN_PF;
            if (sp < T_DIM) buf[j] = p[(long)sp * pstep];
            const float u0 = b2f(u.x);   // candidate
            const float u1 = b2f(u.y);   // forget
            const float u2 = b2f(u.z);   // reset
            const float u3 = b2f(u.w);   // highway
            const float f  = 1.0f / (1.0f + __expf(-(u1 + vf * c + bf)));
            const float c2 = f * (c - u0) + u0;
            const float r  = 1.0f / (1.0f + __expf(-(u2 + vr * c + br)));  // OLD c
            const float hv = r * (c2 - u3) + u3;
            c = c2;
            ho[(long)(s0 + j) * hstep] = __float2bfloat16(hv);
        }
    }
}

// ---------------------------------------------------------------------------
// logits (N=21, K=256) + log_softmax, one thread per row.
__global__ __launch_bounds__(256) void logits_lsm(
    const __hip_bfloat16* __restrict__ fc,   // (M_ROWS, 256) bf16
    const float* __restrict__ lpw,           // (21, 256) f32
    const float* __restrict__ lpb,           // (21,) f32
    float* __restrict__ out, int rows)
{
    const int row = blockIdx.x * 256 + threadIdx.x;
    if (row >= rows) return;
    float acc[AA_DIM];
#pragma unroll
    for (int a = 0; a < AA_DIM; ++a) acc[a] = lpb[a];
    const __hip_bfloat16* hr = fc + (long)row * H_DIM;
    for (int k = 0; k < H_DIM; k += 8) {
        bf16x8 raw = *(const bf16x8*)(hr + k);
#pragma unroll
        for (int j = 0; j < 8; ++j) {
            const float hvj = b2f((unsigned short)raw[j]);
#pragma unroll
            for (int a = 0; a < AA_DIM; ++a)
                acc[a] += hvj * lpw[a * H_DIM + k + j];
        }
    }
    float m = acc[0];
#pragma unroll
    for (int a = 1; a < AA_DIM; ++a) m = fmaxf(m, acc[a]);
    float s = 0.0f;
#pragma unroll
    for (int a = 0; a < AA_DIM; ++a) s += __expf(acc[a] - m);
    const float lse = __logf(s) + m;
#pragma unroll
    for (int a = 0; a < AA_DIM; ++a) out[(long)row * AA_DIM + a] = acc[a] - lse;
}

// ---------------------------------------------------------------------------
extern "C" void kernel_launch(void* const* d_in, const int* in_sizes, int n_in,
                              void* d_out, int out_size, void* d_ws, size_t ws_size,
                              hipStream_t stream)
{
    const float* x     = (const float*)d_in[0];
    const float* w_l0  = (const float*)d_in[2];
    const float* wc_l0 = (const float*)d_in[3];
    const float* b_l0  = (const float*)d_in[4];
    const float* w_l1  = (const float*)d_in[5];
    const float* wc_l1 = (const float*)d_in[6];
    const float* b_l1  = (const float*)d_in[7];
    const float* fc1_w = (const float*)d_in[8];
    const float* fc1_b = (const float*)d_in[9];
    const float* lp_w  = (const float*)d_in[10];
    const float* lp_b  = (const float*)d_in[11];
    float* out = (float*)d_out;

    char* ws = (char*)d_ws;
    __hip_bfloat16* U      = (__hip_bfloat16*)(ws);              // 134,217,728 B
    __hip_bfloat16* h0b    = (__hip_bfloat16*)(ws + 134217728);  //  33,554,432
    __hip_bfloat16* h1b    = (__hip_bfloat16*)(ws + 167772160);  //  33,554,432
    __hip_bfloat16* xb     = (__hip_bfloat16*)(ws + 201326592);  //  16,777,216
    __hip_bfloat16* fcob   = xb;                                 //  alias after GEMM0
    __hip_bfloat16* w0t    = (__hip_bfloat16*)(ws + 218103808);  //  (2048,256)
    __hip_bfloat16* w1t    = (__hip_bfloat16*)(ws + 219152384);  //  (2048,512)
    __hip_bfloat16* fc1wb  = (__hip_bfloat16*)(ws + 221249536);  //  (256,512)

    cvt_bf16<<<(M_ROWS * DIN_DIM + 255) / 256, 256, 0, stream>>>(x, xb, M_ROWS * DIN_DIM);
    cvt_w_sru<<<(DIN_DIM * 2048 + 255) / 256, 256, 0, stream>>>(w_l0, w0t, DIN_DIM);
    cvt_w_sru<<<(512 * 2048 + 255) / 256, 256, 0, stream>>>(w_l1, w1t, 512);
    cvt_bf16<<<(H_DIM * 512 + 255) / 256, 256, 0, stream>>>(fc1_w, fc1wb, H_DIM * 512);

    gemm_bf16<<<dim3(M_ROWS / 128, 2048 / 128), 256, 0, stream>>>(
        xb, w0t, nullptr, U, M_ROWS, 2048, DIN_DIM);
    sru_scan<<<256, 64, 0, stream>>>(U, wc_l0, b_l0, h0b);
    gemm_bf16<<<dim3(M_ROWS / 128, 2048 / 128), 256, 0, stream>>>(
        h0b, w1t, nullptr, U, M_ROWS, 2048, 512);
    sru_scan<<<256, 64, 0, stream>>>(U, wc_l1, b_l1, h1b);
    gemm_bf16<<<dim3(M_ROWS / 128, 256 / 128), 256, 0, stream>>>(
        h1b, fc1wb, fc1_b, fcob, M_ROWS, 256, 512);
    logits_lsm<<<M_ROWS / 256, 256, 0, stream>>>(fcob, lp_w, lp_b, out, M_ROWS);
}

// Round 5
// 510.574 us; speedup vs baseline: 1.3932x; 1.1934x over previous
//
#include <hip/hip_runtime.h>
#include <hip/hip_bf16.h>

// Problem dims (fixed): T=1024, B=32, DIN=256, H=256, AA=21, L=2
#define T_DIM 1024
#define B_DIM 32
#define DIN_DIM 256
#define H_DIM 256
#define AA_DIM 21
#define M_ROWS (B_DIM * T_DIM)   // 32768 rows, row index = b*T + t everywhere

typedef __attribute__((ext_vector_type(8))) short bf16x8;   // 8 bf16 = 4 VGPRs
typedef __attribute__((ext_vector_type(4))) float f32x4;

typedef __attribute__((address_space(3))) void lds_void;
typedef const __attribute__((address_space(1))) void glb_void;

__device__ __forceinline__ void gload_lds16(const void* g, void* l) {
    // global gather (per-lane addr) -> LDS at (wave-uniform base + lane*16)
    __builtin_amdgcn_global_load_lds((glb_void*)g, (lds_void*)l, 16, 0, 0);
}

__device__ __forceinline__ float b2f(unsigned short v) {
    unsigned u = ((unsigned)v) << 16;
    float f;
    __builtin_memcpy(&f, &u, 4);
    return f;
}

__device__ __forceinline__ float sigm(float x) {
    // v_rcp_f32-based sigmoid (~1 ulp rcp; plenty for bf16-rounded outputs)
    return __builtin_amdgcn_rcpf(1.0f + __expf(-x));
}

// ---------------------------------------------------------------------------
// All weight/input converts fused into ONE dispatch (fewer graph gaps).
// seg0: x (B,T,DIN) f32 -> xb bf16 (plain)
// seg1: w_l0 (256,2,4,256) -> w0t bf16 (2048,256), n = dir*1024 + h*4 + k
// seg2: w_l1 (512,2,4,256) -> w1t bf16 (2048,512), same interleave
// seg3: fc1_w (256,512)=(N,K) -> fc1wb bf16 (plain)
#define CVT_N0 8388608
#define CVT_N1 524288
#define CVT_N2 1048576
#define CVT_N3 131072
#define CVT_TOT (CVT_N0 + CVT_N1 + CVT_N2 + CVT_N3)
__global__ __launch_bounds__(256) void cvt_all(
    const float* __restrict__ x,  const float* __restrict__ w0,
    const float* __restrict__ w1, const float* __restrict__ fcw,
    __hip_bfloat16* __restrict__ xb,  __hip_bfloat16* __restrict__ w0t,
    __hip_bfloat16* __restrict__ w1t, __hip_bfloat16* __restrict__ fcwb)
{
    int i = blockIdx.x * 256 + threadIdx.x;
    if (i < CVT_N0) { xb[i] = __float2bfloat16(x[i]); return; }
    i -= CVT_N0;
    if (i < CVT_N1) {   // w0t, K=256; input flat ((kk*2+dir)*4+k)*H + h
        int kk = i >> 11, rem = i & 2047;
        int dir = rem >> 10, k = (rem >> 8) & 3, h = rem & 255;
        w0t[(long)(dir * 1024 + h * 4 + k) * 256 + kk] = __float2bfloat16(w0[i]);
        return;
    }
    i -= CVT_N1;
    if (i < CVT_N2) {   // w1t, K=512
        int kk = i >> 11, rem = i & 2047;
        int dir = rem >> 10, k = (rem >> 8) & 3, h = rem & 255;
        w1t[(long)(dir * 1024 + h * 4 + k) * 512 + kk] = __float2bfloat16(w1[i]);
        return;
    }
    i -= CVT_N2;
    if (i < CVT_N3) fcwb[i] = __float2bfloat16(fcw[i]);
}

// ---------------------------------------------------------------------------
// bf16 GEMM: C(M,N) = A(M,K) * Bt(N,K)^T  [+ bias], C stored bf16.
// 128x128 tile, BK=64 (2 MFMA k-steps per stage -> half the barrier drains).
// Grid: x = N-block (fast), y = M-block  -> consecutive blocks share A rows
// (L2/L3 A-reuse). Staging: row-major 16-row x 64B chunks per global_load_lds
// with XOR k-quad swizzle (slot q holds global quad q ^ ((row>>1)&3)) ->
// conflict-free ds_read_b128 AND coalesced global fetch.
// Epilogue: LDS-staged coalesced C store (no read-modify-write).
__global__ __launch_bounds__(256) void gemm_bf16(
    const __hip_bfloat16* __restrict__ A,
    const __hip_bfloat16* __restrict__ Bt,
    const float* __restrict__ bias,   // len N or nullptr
    __hip_bfloat16* __restrict__ C,
    int M, int N, int K)
{
    // A tile bytes [0,16384): sub-chunk (rc,kh) at rc*2048 + kh*1024,
    //   within: 16 rows x 64B (4 swizzled 16B k-quad slots per row)
    // B tile bytes [16384,32768): same layout
    // epilogue reuse: [128 rows][stride 144B] bf16 C-tile (18432 B)
    __shared__ __align__(16) char smb[32768];

    const int tid  = threadIdx.x;
    const int lane = tid & 63;
    const int wave = tid >> 6;
    const int wm = wave & 1;
    const int wn = wave >> 1;
    const long n0 = (long)blockIdx.x * 128;   // N-fast for A-reuse
    const long m0 = (long)blockIdx.y * 128;

    f32x4 acc[4][4] = {};

    // staging lane mapping
    const int ldrow = lane >> 2;                    // row within 16-row chunk
    const int ldq   = lane & 3;                     // LDS k-quad slot
    const int gq    = ldq ^ ((ldrow >> 1) & 3);     // global k-quad fetched
    const int gkoff = gq * 8;                       // elements

    // fragment read mapping
    const int fr = lane & 15;
    const int kq = lane >> 4;
    const int sw = (kq ^ ((fr >> 1) & 3)) * 16;     // swizzled slot byte offset

    for (int kb = 0; kb < K; kb += 64) {
        __syncthreads();
#pragma unroll
        for (int i = 0; i < 4; ++i) {
            const int cid = wave * 4 + i;       // 0..15
            const int rc  = cid >> 1;           // row-chunk 0..7
            const int kh  = cid & 1;            // k-half 0..1
            const long row = rc * 16 + ldrow;
            const int koff = kb + kh * 32 + gkoff;
            gload_lds16(A  + (m0 + row) * (long)K + koff,
                        smb + rc * 2048 + kh * 1024);
            gload_lds16(Bt + (n0 + row) * (long)K + koff,
                        smb + 16384 + rc * 2048 + kh * 1024);
        }
        __syncthreads();   // drains vmcnt(0): staged data visible

#pragma unroll
        for (int s = 0; s < 2; ++s) {
            bf16x8 af[4], bfv[4];
#pragma unroll
            for (int i = 0; i < 4; ++i) {
                af[i]  = *(const bf16x8*)(smb + (wm * 4 + i) * 2048 + s * 1024 + fr * 64 + sw);
                bfv[i] = *(const bf16x8*)(smb + 16384 + (wn * 4 + i) * 2048 + s * 1024 + fr * 64 + sw);
            }
#pragma unroll
            for (int i = 0; i < 4; ++i)
#pragma unroll
                for (int j = 0; j < 4; ++j)
                    acc[i][j] = __builtin_amdgcn_mfma_f32_16x16x32_bf16(
                        af[i], bfv[j], acc[i][j], 0, 0, 0);
        }
    }

    // ---- epilogue: C/D layout col=lane&15, row=(lane>>4)*4+reg ----
    const int col_l = lane & 15;
    const int row_l = (lane >> 4) * 4;
    __hip_bfloat16* smC = (__hip_bfloat16*)smb;   // stride 72 bf16 = 144 B
#pragma unroll
    for (int p = 0; p < 2; ++p) {
        __syncthreads();   // prior LDS reads done
        if (wn == p) {
#pragma unroll
            for (int j = 0; j < 4; ++j) {
                const long gc = n0 + p * 64 + j * 16 + col_l;
                const float bv = bias ? bias[gc] : 0.0f;
#pragma unroll
                for (int i = 0; i < 4; ++i)
#pragma unroll
                    for (int r = 0; r < 4; ++r)
                        smC[(wm * 64 + i * 16 + row_l + r) * 72 + j * 16 + col_l] =
                            __float2bfloat16(acc[i][j][r] + bv);
            }
        }
        __syncthreads();
        const int orow = tid >> 3;          // 0..31
        const int ocs  = (tid & 7) * 8;     // col start, bf16 units
#pragma unroll
        for (int rnd = 0; rnd < 4; ++rnd) {
            const int rr = rnd * 32 + orow;
            bf16x8 v = *(const bf16x8*)(smC + rr * 72 + ocs);
            *(bf16x8*)(C + (m0 + rr) * (long)N + n0 + p * 64 + ocs) = v;
        }
    }
}

// ---------------------------------------------------------------------------
// SRU scan, one thread per (dir, b, h) recurrence; 16384 threads = 1 wave/CU.
// U layout INTERLEAVED: col = dir*1024 + h*4 + k -> one ushort4 (8B) load per
// step. Depth-32 register prefetch ring (16 KB in flight per CU).
#define SCAN_PF 32
__global__ __launch_bounds__(64) void sru_scan(
    const __hip_bfloat16* __restrict__ U,
    const float* __restrict__ wc,    // (2,2,H): [dir][vf,vr][h]
    const float* __restrict__ bias,  // (2,2,H): [dir][bf,br][h]
    __hip_bfloat16* __restrict__ hout)
{
    const int id  = blockIdx.x * 64 + threadIdx.x;  // 0..16383
    const int dir = id >> 13;
    const int rem = id & 8191;
    const int b   = rem >> 8;
    const int h   = rem & 255;

    const float vf = wc[(dir * 2 + 0) * H_DIM + h];
    const float vr = wc[(dir * 2 + 1) * H_DIM + h];
    const float bf = bias[(dir * 2 + 0) * H_DIM + h];
    const float br = bias[(dir * 2 + 1) * H_DIM + h];

    const long row0  = (long)b * T_DIM + (dir ? (T_DIM - 1) : 0);
    const long rstep = dir ? -2048 : 2048;
    const ushort4* p = (const ushort4*)(U + row0 * 2048 + dir * 1024 + (h << 2));
    const long pstep = rstep / 4;

    __hip_bfloat16* ho = hout + row0 * 512 + dir * 256 + h;
    const long hstep = dir ? -512 : 512;

    ushort4 buf[SCAN_PF];
#pragma unroll
    for (int j = 0; j < SCAN_PF; ++j) buf[j] = p[j * pstep];

    float c = 0.0f;
    for (int s0 = 0; s0 < T_DIM; s0 += SCAN_PF) {
#pragma unroll
        for (int j = 0; j < SCAN_PF; ++j) {
            const ushort4 u = buf[j];
            const int sp = s0 + j + SCAN_PF;
            if (sp < T_DIM) buf[j] = p[(long)sp * pstep];
            const float u0 = b2f(u.x);   // candidate
            const float u1 = b2f(u.y);   // forget
            const float u2 = b2f(u.z);   // reset
            const float u3 = b2f(u.w);   // highway
            const float f  = sigm(u1 + vf * c + bf);
            const float c2 = f * (c - u0) + u0;
            const float r  = sigm(u2 + vr * c + br);   // uses OLD c
            const float hv = r * (c2 - u3) + u3;
            c = c2;
            ho[(long)(s0 + j) * hstep] = __float2bfloat16(hv);
        }
    }
}

// ---------------------------------------------------------------------------
// logits (N=21, K=256) + log_softmax, one thread per row.
__global__ __launch_bounds__(256) void logits_lsm(
    const __hip_bfloat16* __restrict__ fc,   // (M_ROWS, 256) bf16
    const float* __restrict__ lpw,           // (21, 256) f32
    const float* __restrict__ lpb,           // (21,) f32
    float* __restrict__ out, int rows)
{
    const int row = blockIdx.x * 256 + threadIdx.x;
    if (row >= rows) return;
    float acc[AA_DIM];
#pragma unroll
    for (int a = 0; a < AA_DIM; ++a) acc[a] = lpb[a];
    const __hip_bfloat16* hr = fc + (long)row * H_DIM;
    for (int k = 0; k < H_DIM; k += 8) {
        bf16x8 raw = *(const bf16x8*)(hr + k);
#pragma unroll
        for (int j = 0; j < 8; ++j) {
            const float hvj = b2f((unsigned short)raw[j]);
#pragma unroll
            for (int a = 0; a < AA_DIM; ++a)
                acc[a] += hvj * lpw[a * H_DIM + k + j];
        }
    }
    float m = acc[0];
#pragma unroll
    for (int a = 1; a < AA_DIM; ++a) m = fmaxf(m, acc[a]);
    float s = 0.0f;
#pragma unroll
    for (int a = 0; a < AA_DIM; ++a) s += __expf(acc[a] - m);
    const float lse = __logf(s) + m;
#pragma unroll
    for (int a = 0; a < AA_DIM; ++a) out[(long)row * AA_DIM + a] = acc[a] - lse;
}

// ---------------------------------------------------------------------------
extern "C" void kernel_launch(void* const* d_in, const int* in_sizes, int n_in,
                              void* d_out, int out_size, void* d_ws, size_t ws_size,
                              hipStream_t stream)
{
    const float* x     = (const float*)d_in[0];
    const float* w_l0  = (const float*)d_in[2];
    const float* wc_l0 = (const float*)d_in[3];
    const float* b_l0  = (const float*)d_in[4];
    const float* w_l1  = (const float*)d_in[5];
    const float* wc_l1 = (const float*)d_in[6];
    const float* b_l1  = (const float*)d_in[7];
    const float* fc1_w = (const float*)d_in[8];
    const float* fc1_b = (const float*)d_in[9];
    const float* lp_w  = (const float*)d_in[10];
    const float* lp_b  = (const float*)d_in[11];
    float* out = (float*)d_out;

    char* ws = (char*)d_ws;
    __hip_bfloat16* U      = (__hip_bfloat16*)(ws);              // 134,217,728 B
    __hip_bfloat16* h0b    = (__hip_bfloat16*)(ws + 134217728);  //  33,554,432
    __hip_bfloat16* h1b    = (__hip_bfloat16*)(ws + 167772160);  //  33,554,432
    __hip_bfloat16* xb     = (__hip_bfloat16*)(ws + 201326592);  //  16,777,216
    __hip_bfloat16* fcob   = xb;                                 //  alias after GEMM0
    __hip_bfloat16* w0t    = (__hip_bfloat16*)(ws + 218103808);  //  (2048,256)
    __hip_bfloat16* w1t    = (__hip_bfloat16*)(ws + 219152384);  //  (2048,512)
    __hip_bfloat16* fc1wb  = (__hip_bfloat16*)(ws + 221249536);  //  (256,512)

    cvt_all<<<(CVT_TOT + 255) / 256, 256, 0, stream>>>(
        x, w_l0, w_l1, fc1_w, xb, w0t, w1t, fc1wb);

    gemm_bf16<<<dim3(2048 / 128, M_ROWS / 128), 256, 0, stream>>>(
        xb, w0t, nullptr, U, M_ROWS, 2048, DIN_DIM);
    sru_scan<<<256, 64, 0, stream>>>(U, wc_l0, b_l0, h0b);
    gemm_bf16<<<dim3(2048 / 128, M_ROWS / 128), 256, 0, stream>>>(
        h0b, w1t, nullptr, U, M_ROWS, 2048, 512);
    sru_scan<<<256, 64, 0, stream>>>(U, wc_l1, b_l1, h1b);
    gemm_bf16<<<dim3(256 / 128, M_ROWS / 128), 256, 0, stream>>>(
        h1b, fc1wb, fc1_b, fcob, M_ROWS, 256, 512);
    logits_lsm<<<M_ROWS / 256, 256, 0, stream>>>(fcob, lp_w, lp_b, out, M_ROWS);
}

// Round 6
// 507.049 us; speedup vs baseline: 1.4029x; 1.0070x over previous
//
#include <hip/hip_runtime.h>
#include <hip/hip_bf16.h>

// Problem dims (fixed): T=1024, B=32, DIN=256, H=256, AA=21, L=2
#define T_DIM 1024
#define B_DIM 32
#define DIN_DIM 256
#define H_DIM 256
#define AA_DIM 21
#define M_ROWS (B_DIM * T_DIM)   // 32768 rows, row index = b*T + t everywhere

typedef __attribute__((ext_vector_type(8))) short bf16x8;   // 8 bf16 = 4 VGPRs
typedef __attribute__((ext_vector_type(4))) float f32x4;

typedef __attribute__((address_space(3))) void lds_void;
typedef const __attribute__((address_space(1))) void glb_void;

__device__ __forceinline__ void gload_lds16(const void* g, void* l) {
    // global gather (per-lane addr) -> LDS at (wave-uniform base + lane*16)
    __builtin_amdgcn_global_load_lds((glb_void*)g, (lds_void*)l, 16, 0, 0);
}

__device__ __forceinline__ float b2f(unsigned short v) {
    unsigned u = ((unsigned)v) << 16;
    float f;
    __builtin_memcpy(&f, &u, 4);
    return f;
}

// ---------------------------------------------------------------------------
// All weight/input converts fused into ONE dispatch.
// seg0: x (B,T,DIN) f32 -> xb bf16 (plain)
// seg1: w_l0 (256,2,4,256) -> w0t bf16 (2048,256), n = dir*1024 + h*4 + k
// seg2: w_l1 (512,2,4,256) -> w1t bf16 (2048,512), same interleave
// seg3: fc1_w (256,512)=(N,K) -> fc1wb bf16 (plain)
#define CVT_N0 8388608
#define CVT_N1 524288
#define CVT_N2 1048576
#define CVT_N3 131072
#define CVT_TOT (CVT_N0 + CVT_N1 + CVT_N2 + CVT_N3)
__global__ __launch_bounds__(256) void cvt_all(
    const float* __restrict__ x,  const float* __restrict__ w0,
    const float* __restrict__ w1, const float* __restrict__ fcw,
    __hip_bfloat16* __restrict__ xb,  __hip_bfloat16* __restrict__ w0t,
    __hip_bfloat16* __restrict__ w1t, __hip_bfloat16* __restrict__ fcwb)
{
    int i = blockIdx.x * 256 + threadIdx.x;
    if (i < CVT_N0) { xb[i] = __float2bfloat16(x[i]); return; }
    i -= CVT_N0;
    if (i < CVT_N1) {   // w0t, K=256; input flat ((kk*2+dir)*4+k)*H + h
        int kk = i >> 11, rem = i & 2047;
        int dir = rem >> 10, k = (rem >> 8) & 3, h = rem & 255;
        w0t[(long)(dir * 1024 + h * 4 + k) * 256 + kk] = __float2bfloat16(w0[i]);
        return;
    }
    i -= CVT_N1;
    if (i < CVT_N2) {   // w1t, K=512
        int kk = i >> 11, rem = i & 2047;
        int dir = rem >> 10, k = (rem >> 8) & 3, h = rem & 255;
        w1t[(long)(dir * 1024 + h * 4 + k) * 512 + kk] = __float2bfloat16(w1[i]);
        return;
    }
    i -= CVT_N2;
    if (i < CVT_N3) fcwb[i] = __float2bfloat16(fcw[i]);
}

// ---------------------------------------------------------------------------
// bf16 GEMM: C(M,N) = A(M,K) * Bt(N,K)^T  [+ bias], C stored bf16.
// 128x128 tile, BK=64. 1-D grid with XCD-aware swizzle: all NB n-blocks of an
// M-tile land on ONE XCD (L2-resident A-tile + B). Staging: row-major 16-row x
// 64B chunks per global_load_lds with XOR k-quad swizzle -> conflict-free
// ds_read_b128 AND coalesced fetch. Epilogue: LDS-staged coalesced C store.
// Grid size must be (M/128)*NB, with M/128 a multiple of 8, NB = 1<<nbShift.
__global__ __launch_bounds__(256) void gemm_bf16(
    const __hip_bfloat16* __restrict__ A,
    const __hip_bfloat16* __restrict__ Bt,
    const float* __restrict__ bias,   // len N or nullptr
    __hip_bfloat16* __restrict__ C,
    int M, int N, int K, int nbShift)
{
    __shared__ __align__(16) char smb[32768];

    const int tid  = threadIdx.x;
    const int lane = tid & 63;
    const int wave = tid >> 6;
    const int wm = wave & 1;
    const int wn = wave >> 1;

    // XCD swizzle: linear block id L -> XCD = L&7 (dispatch heuristic).
    // nb = s & (NB-1), mb = (s>>nbShift)*8 + (L&7): one XCD owns all nb of mb.
    const int L   = blockIdx.x;
    const int s   = L >> 3;
    const int nb  = s & ((1 << nbShift) - 1);
    const int mb  = ((s >> nbShift) << 3) + (L & 7);
    const long n0 = (long)nb * 128;
    const long m0 = (long)mb * 128;

    f32x4 acc[4][4] = {};

    // staging lane mapping
    const int ldrow = lane >> 2;                    // row within 16-row chunk
    const int ldq   = lane & 3;                     // LDS k-quad slot
    const int gq    = ldq ^ ((ldrow >> 1) & 3);     // global k-quad fetched
    const int gkoff = gq * 8;                       // elements

    // fragment read mapping
    const int fr = lane & 15;
    const int kq = lane >> 4;
    const int sw = (kq ^ ((fr >> 1) & 3)) * 16;     // swizzled slot byte offset

    for (int kb = 0; kb < K; kb += 64) {
        __syncthreads();
#pragma unroll
        for (int i = 0; i < 4; ++i) {
            const int cid = wave * 4 + i;       // 0..15
            const int rc  = cid >> 1;           // row-chunk 0..7
            const int kh  = cid & 1;            // k-half 0..1
            const long row = rc * 16 + ldrow;
            const int koff = kb + kh * 32 + gkoff;
            gload_lds16(A  + (m0 + row) * (long)K + koff,
                        smb + rc * 2048 + kh * 1024);
            gload_lds16(Bt + (n0 + row) * (long)K + koff,
                        smb + 16384 + rc * 2048 + kh * 1024);
        }
        __syncthreads();   // drains vmcnt(0): staged data visible

#pragma unroll
        for (int ss = 0; ss < 2; ++ss) {
            bf16x8 af[4], bfv[4];
#pragma unroll
            for (int i = 0; i < 4; ++i) {
                af[i]  = *(const bf16x8*)(smb + (wm * 4 + i) * 2048 + ss * 1024 + fr * 64 + sw);
                bfv[i] = *(const bf16x8*)(smb + 16384 + (wn * 4 + i) * 2048 + ss * 1024 + fr * 64 + sw);
            }
#pragma unroll
            for (int i = 0; i < 4; ++i)
#pragma unroll
                for (int j = 0; j < 4; ++j)
                    acc[i][j] = __builtin_amdgcn_mfma_f32_16x16x32_bf16(
                        af[i], bfv[j], acc[i][j], 0, 0, 0);
        }
    }

    // ---- epilogue: C/D layout col=lane&15, row=(lane>>4)*4+reg ----
    const int col_l = lane & 15;
    const int row_l = (lane >> 4) * 4;
    __hip_bfloat16* smC = (__hip_bfloat16*)smb;   // stride 72 bf16 = 144 B
#pragma unroll
    for (int p = 0; p < 2; ++p) {
        __syncthreads();   // prior LDS reads done
        if (wn == p) {
#pragma unroll
            for (int j = 0; j < 4; ++j) {
                const long gc = n0 + p * 64 + j * 16 + col_l;
                const float bv = bias ? bias[gc] : 0.0f;
#pragma unroll
                for (int i = 0; i < 4; ++i)
#pragma unroll
                    for (int r = 0; r < 4; ++r)
                        smC[(wm * 64 + i * 16 + row_l + r) * 72 + j * 16 + col_l] =
                            __float2bfloat16(acc[i][j][r] + bv);
            }
        }
        __syncthreads();
        const int orow = tid >> 3;          // 0..31
        const int ocs  = (tid & 7) * 8;     // col start, bf16 units
#pragma unroll
        for (int rnd = 0; rnd < 4; ++rnd) {
            const int rr = rnd * 32 + orow;
            bf16x8 v = *(const bf16x8*)(smC + rr * 72 + ocs);
            *(bf16x8*)(C + (m0 + rr) * (long)N + n0 + p * 64 + ocs) = v;
        }
    }
}

// ---------------------------------------------------------------------------
// SRU scan, one thread per (dir, b, h) recurrence; 16384 threads = 1 wave/CU.
// U layout INTERLEAVED: col = dir*1024 + h*4 + k -> one 8B load per step.
// Depth-32 prefetch ring. Serial c-chain minimized: exp2-based sigmoid with
// scale folded into precomputed constants -> fma -> v_exp -> add -> rcp -> fma
// (~28 cyc/step loop-carried latency).
#define SCAN_PF 32
__global__ __launch_bounds__(64) void sru_scan(
    const __hip_bfloat16* __restrict__ U,
    const float* __restrict__ wc,    // (2,2,H): [dir][vf,vr][h]
    const float* __restrict__ bias,  // (2,2,H): [dir][bf,br][h]
    __hip_bfloat16* __restrict__ hout)
{
    const int id  = blockIdx.x * 64 + threadIdx.x;  // 0..16383
    const int dir = id >> 13;
    const int rem = id & 8191;
    const int b   = rem >> 8;
    const int h   = rem & 255;

    const float LOG2E = 1.44269504088896340736f;
    const float vf = wc[(dir * 2 + 0) * H_DIM + h];
    const float vr = wc[(dir * 2 + 1) * H_DIM + h];
    const float bf = bias[(dir * 2 + 0) * H_DIM + h];
    const float br = bias[(dir * 2 + 1) * H_DIM + h];
    // sigmoid(x) = rcp(1 + exp2(-LOG2E*x)); x = u + v*c + b
    const float nvf = -LOG2E * vf, nbf = -LOG2E * bf;
    const float nvr = -LOG2E * vr, nbr = -LOG2E * br;

    const long row0 = (long)b * T_DIM + (dir ? (T_DIM - 1) : 0);
    const uint2* p  = (const uint2*)(U + row0 * 2048 + dir * 1024 + (h << 2));
    const long pstep = dir ? -512 : 512;    // uint2 units (row stride 2048 bf16)

    __hip_bfloat16* ho = hout + row0 * 512 + dir * 256 + h;
    const long hstep = dir ? -512 : 512;

    uint2 buf[SCAN_PF];
#pragma unroll
    for (int j = 0; j < SCAN_PF; ++j) buf[j] = p[j * pstep];

    float c = 0.0f;
    for (int s0 = 0; s0 < T_DIM; s0 += SCAN_PF) {
#pragma unroll
        for (int j = 0; j < SCAN_PF; ++j) {
            const uint2 u = buf[j];
            const int sp = s0 + j + SCAN_PF;
            if (sp < T_DIM) buf[j] = p[(long)sp * pstep];
            // unpack: [u0,u1] in u.x, [u2,u3] in u.y (bf16 pairs)
            float u0, u1, u2, u3;
            {
                unsigned a0 = u.x << 16, a1 = u.x & 0xffff0000u;
                unsigned a2 = u.y << 16, a3 = u.y & 0xffff0000u;
                __builtin_memcpy(&u0, &a0, 4); __builtin_memcpy(&u1, &a1, 4);
                __builtin_memcpy(&u2, &a2, 4); __builtin_memcpy(&u3, &a3, 4);
            }
            // independent-of-c work (schedules off the serial chain)
            const float nf0 = __builtin_fmaf(-LOG2E, u1, nbf);
            const float nr0 = __builtin_fmaf(-LOG2E, u2, nbr);
            // serial chain (r uses OLD c -> parallel with f chain)
            const float ef = __builtin_amdgcn_exp2f(__builtin_fmaf(nvf, c, nf0));
            const float er = __builtin_amdgcn_exp2f(__builtin_fmaf(nvr, c, nr0));
            const float f  = __builtin_amdgcn_rcpf(1.0f + ef);
            const float r  = __builtin_amdgcn_rcpf(1.0f + er);
            const float c2 = __builtin_fmaf(f, c - u0, u0);
            const float hv = __builtin_fmaf(r, c2 - u3, u3);
            c = c2;
            ho[(long)(s0 + j) * hstep] = __float2bfloat16(hv);
        }
    }
}

// ---------------------------------------------------------------------------
// logits (N=21, K=256) + log_softmax, one thread per row.
__global__ __launch_bounds__(256) void logits_lsm(
    const __hip_bfloat16* __restrict__ fc,   // (M_ROWS, 256) bf16
    const float* __restrict__ lpw,           // (21, 256) f32
    const float* __restrict__ lpb,           // (21,) f32
    float* __restrict__ out, int rows)
{
    const int row = blockIdx.x * 256 + threadIdx.x;
    if (row >= rows) return;
    float acc[AA_DIM];
#pragma unroll
    for (int a = 0; a < AA_DIM; ++a) acc[a] = lpb[a];
    const __hip_bfloat16* hr = fc + (long)row * H_DIM;
    for (int k = 0; k < H_DIM; k += 8) {
        bf16x8 raw = *(const bf16x8*)(hr + k);
#pragma unroll
        for (int j = 0; j < 8; ++j) {
            const float hvj = b2f((unsigned short)raw[j]);
#pragma unroll
            for (int a = 0; a < AA_DIM; ++a)
                acc[a] += hvj * lpw[a * H_DIM + k + j];
        }
    }
    float m = acc[0];
#pragma unroll
    for (int a = 1; a < AA_DIM; ++a) m = fmaxf(m, acc[a]);
    float s = 0.0f;
#pragma unroll
    for (int a = 0; a < AA_DIM; ++a) s += __expf(acc[a] - m);
    const float lse = __logf(s) + m;
#pragma unroll
    for (int a = 0; a < AA_DIM; ++a) out[(long)row * AA_DIM + a] = acc[a] - lse;
}

// ---------------------------------------------------------------------------
extern "C" void kernel_launch(void* const* d_in, const int* in_sizes, int n_in,
                              void* d_out, int out_size, void* d_ws, size_t ws_size,
                              hipStream_t stream)
{
    const float* x     = (const float*)d_in[0];
    const float* w_l0  = (const float*)d_in[2];
    const float* wc_l0 = (const float*)d_in[3];
    const float* b_l0  = (const float*)d_in[4];
    const float* w_l1  = (const float*)d_in[5];
    const float* wc_l1 = (const float*)d_in[6];
    const float* b_l1  = (const float*)d_in[7];
    const float* fc1_w = (const float*)d_in[8];
    const float* fc1_b = (const float*)d_in[9];
    const float* lp_w  = (const float*)d_in[10];
    const float* lp_b  = (const float*)d_in[11];
    float* out = (float*)d_out;

    char* ws = (char*)d_ws;
    __hip_bfloat16* U      = (__hip_bfloat16*)(ws);              // 134,217,728 B
    __hip_bfloat16* h0b    = (__hip_bfloat16*)(ws + 134217728);  //  33,554,432
    __hip_bfloat16* h1b    = (__hip_bfloat16*)(ws + 167772160);  //  33,554,432
    __hip_bfloat16* xb     = (__hip_bfloat16*)(ws + 201326592);  //  16,777,216
    __hip_bfloat16* fcob   = xb;                                 //  alias after GEMM0
    __hip_bfloat16* w0t    = (__hip_bfloat16*)(ws + 218103808);  //  (2048,256)
    __hip_bfloat16* w1t    = (__hip_bfloat16*)(ws + 219152384);  //  (2048,512)
    __hip_bfloat16* fc1wb  = (__hip_bfloat16*)(ws + 221249536);  //  (256,512)

    cvt_all<<<(CVT_TOT + 255) / 256, 256, 0, stream>>>(
        x, w_l0, w_l1, fc1_w, xb, w0t, w1t, fc1wb);

    // grid = MB*NB (1-D); MB=256, NB=16 -> 4096 blocks, nbShift=4
    gemm_bf16<<<4096, 256, 0, stream>>>(
        xb, w0t, nullptr, U, M_ROWS, 2048, DIN_DIM, 4);
    sru_scan<<<256, 64, 0, stream>>>(U, wc_l0, b_l0, h0b);
    gemm_bf16<<<4096, 256, 0, stream>>>(
        h0b, w1t, nullptr, U, M_ROWS, 2048, 512, 4);
    sru_scan<<<256, 64, 0, stream>>>(U, wc_l1, b_l1, h1b);
    // NB=2 -> 512 blocks, nbShift=1
    gemm_bf16<<<512, 256, 0, stream>>>(
        h1b, fc1wb, fc1_b, fcob, M_ROWS, 256, 512, 1);
    logits_lsm<<<M_ROWS / 256, 256, 0, stream>>>(fcob, lp_w, lp_b, out, M_ROWS);
}

// Round 7
// 466.610 us; speedup vs baseline: 1.5245x; 1.0867x over previous
//
#include <hip/hip_runtime.h>
#include <hip/hip_bf16.h>

// Problem dims (fixed): T=1024, B=32, DIN=256, H=256, AA=21, L=2
#define T_DIM 1024
#define B_DIM 32
#define DIN_DIM 256
#define H_DIM 256
#define AA_DIM 21
#define M_ROWS (B_DIM * T_DIM)   // 32768 rows, row index = b*T + t everywhere

typedef __attribute__((ext_vector_type(8))) short bf16x8;   // 8 bf16 = 4 VGPRs
typedef __attribute__((ext_vector_type(4))) float f32x4;

typedef __attribute__((address_space(3))) void lds_void;
typedef const __attribute__((address_space(1))) void glb_void;

__device__ __forceinline__ void gload_lds16(const void* g, void* l) {
    // global gather (per-lane addr) -> LDS at (wave-uniform base + lane*16)
    __builtin_amdgcn_global_load_lds((glb_void*)g, (lds_void*)l, 16, 0, 0);
}

__device__ __forceinline__ float b2f(unsigned short v) {
    unsigned u = ((unsigned)v) << 16;
    float f;
    __builtin_memcpy(&f, &u, 4);
    return f;
}

// ---------------------------------------------------------------------------
// All weight/input converts fused into ONE dispatch.
// seg0: x (B,T,DIN) f32 -> xb bf16 (plain)
// seg1: w_l0 (256,2,4,256) -> w0t bf16 (2048,256), n = dir*1024 + h*4 + k
// seg2: w_l1 (512,2,4,256) -> w1t bf16 (2048,512), same interleave
// seg3: fc1_w (256,512)=(N,K) -> fc1wb bf16 (plain)
// seg4: lp_w (21,256) f32 -> lpwb bf16 (32,256), rows 21..31 zero
#define CVT_N0 8388608
#define CVT_N1 524288
#define CVT_N2 1048576
#define CVT_N3 131072
#define CVT_N4 8192
#define CVT_TOT (CVT_N0 + CVT_N1 + CVT_N2 + CVT_N3 + CVT_N4)
__global__ __launch_bounds__(256) void cvt_all(
    const float* __restrict__ x,  const float* __restrict__ w0,
    const float* __restrict__ w1, const float* __restrict__ fcw,
    const float* __restrict__ lpw,
    __hip_bfloat16* __restrict__ xb,  __hip_bfloat16* __restrict__ w0t,
    __hip_bfloat16* __restrict__ w1t, __hip_bfloat16* __restrict__ fcwb,
    __hip_bfloat16* __restrict__ lpwb)
{
    int i = blockIdx.x * 256 + threadIdx.x;
    if (i < CVT_N0) { xb[i] = __float2bfloat16(x[i]); return; }
    i -= CVT_N0;
    if (i < CVT_N1) {   // w0t, K=256; input flat ((kk*2+dir)*4+k)*H + h
        int kk = i >> 11, rem = i & 2047;
        int dir = rem >> 10, k = (rem >> 8) & 3, h = rem & 255;
        w0t[(long)(dir * 1024 + h * 4 + k) * 256 + kk] = __float2bfloat16(w0[i]);
        return;
    }
    i -= CVT_N1;
    if (i < CVT_N2) {   // w1t, K=512
        int kk = i >> 11, rem = i & 2047;
        int dir = rem >> 10, k = (rem >> 8) & 3, h = rem & 255;
        w1t[(long)(dir * 1024 + h * 4 + k) * 512 + kk] = __float2bfloat16(w1[i]);
        return;
    }
    i -= CVT_N2;
    if (i < CVT_N3) { fcwb[i] = __float2bfloat16(fcw[i]); return; }
    i -= CVT_N3;
    if (i < CVT_N4) {   // lpwb (32,256), zero-padded past row 20
        int n = i >> 8, k = i & 255;
        lpwb[i] = __float2bfloat16(n < AA_DIM ? lpw[n * 256 + k] : 0.0f);
    }
}

// ---------------------------------------------------------------------------
// bf16 GEMM: C(M,N) = A(M,K) * Bt(N,K)^T  [+ bias], C stored bf16.
// 128x128 tile, BK=64. 1-D grid with XCD-aware swizzle (all NB n-blocks of an
// M-tile on ONE XCD -> L2-resident A-tile + B). Staging: row-major 16-row x
// 64B chunks with XOR k-quad swizzle -> conflict-free ds_read_b128 AND
// coalesced fetch. Single-pass LDS epilogue (2 barriers, all waves active).
__global__ __launch_bounds__(256) void gemm_bf16(
    const __hip_bfloat16* __restrict__ A,
    const __hip_bfloat16* __restrict__ Bt,
    const float* __restrict__ bias,   // len N or nullptr
    __hip_bfloat16* __restrict__ C,
    int M, int N, int K, int nbShift)
{
    // staging [0,32768); epilogue C-tile 128 rows x stride 132 bf16 = 33792 B
    __shared__ __align__(16) char smb[33792];

    const int tid  = threadIdx.x;
    const int lane = tid & 63;
    const int wave = tid >> 6;
    const int wm = wave & 1;
    const int wn = wave >> 1;

    const int L   = blockIdx.x;
    const int s   = L >> 3;
    const int nb  = s & ((1 << nbShift) - 1);
    const int mb  = ((s >> nbShift) << 3) + (L & 7);
    const long n0 = (long)nb * 128;
    const long m0 = (long)mb * 128;

    f32x4 acc[4][4] = {};

    // staging lane mapping
    const int ldrow = lane >> 2;                    // row within 16-row chunk
    const int ldq   = lane & 3;                     // LDS k-quad slot
    const int gq    = ldq ^ ((ldrow >> 1) & 3);     // global k-quad fetched
    const int gkoff = gq * 8;                       // elements

    // fragment read mapping
    const int fr = lane & 15;
    const int kq = lane >> 4;
    const int sw = (kq ^ ((fr >> 1) & 3)) * 16;     // swizzled slot byte offset

    for (int kb = 0; kb < K; kb += 64) {
        __syncthreads();
#pragma unroll
        for (int i = 0; i < 4; ++i) {
            const int cid = wave * 4 + i;       // 0..15
            const int rc  = cid >> 1;           // row-chunk 0..7
            const int kh  = cid & 1;            // k-half 0..1
            const long row = rc * 16 + ldrow;
            const int koff = kb + kh * 32 + gkoff;
            gload_lds16(A  + (m0 + row) * (long)K + koff,
                        smb + rc * 2048 + kh * 1024);
            gload_lds16(Bt + (n0 + row) * (long)K + koff,
                        smb + 16384 + rc * 2048 + kh * 1024);
        }
        __syncthreads();   // drains vmcnt(0): staged data visible

#pragma unroll
        for (int ss = 0; ss < 2; ++ss) {
            bf16x8 af[4], bfv[4];
#pragma unroll
            for (int i = 0; i < 4; ++i) {
                af[i]  = *(const bf16x8*)(smb + (wm * 4 + i) * 2048 + ss * 1024 + fr * 64 + sw);
                bfv[i] = *(const bf16x8*)(smb + 16384 + (wn * 4 + i) * 2048 + ss * 1024 + fr * 64 + sw);
            }
#pragma unroll
            for (int i = 0; i < 4; ++i)
#pragma unroll
                for (int j = 0; j < 4; ++j)
                    acc[i][j] = __builtin_amdgcn_mfma_f32_16x16x32_bf16(
                        af[i], bfv[j], acc[i][j], 0, 0, 0);
        }
    }

    // ---- single-pass epilogue: C/D layout col=lane&15, row=(lane>>4)*4+reg --
    const int col_l = lane & 15;
    const int row_l = (lane >> 4) * 4;
    __hip_bfloat16* smC = (__hip_bfloat16*)smb;   // stride 132 bf16 = 264 B
    __syncthreads();   // K-loop LDS reads done before overwrite
#pragma unroll
    for (int j = 0; j < 4; ++j) {
        const long gc = n0 + wn * 64 + j * 16 + col_l;
        const float bv = bias ? bias[gc] : 0.0f;
#pragma unroll
        for (int i = 0; i < 4; ++i)
#pragma unroll
            for (int r = 0; r < 4; ++r)
                smC[(wm * 64 + i * 16 + row_l + r) * 132 + wn * 64 + j * 16 + col_l] =
                    __float2bfloat16(acc[i][j][r] + bv);
    }
    __syncthreads();
    const int erow = tid >> 1;          // 0..127
    const int ecol = (tid & 1) * 64;    // bf16 units
#pragma unroll
    for (int s2 = 0; s2 < 8; ++s2) {
        bf16x8 v = *(const bf16x8*)(smC + erow * 132 + ecol + s2 * 8);
        *(bf16x8*)(C + (m0 + erow) * (long)N + n0 + ecol + s2 * 8) = v;
    }
}

// ---------------------------------------------------------------------------
// SRU scan, one thread per (dir, b, h) recurrence; 16384 threads = 1 wave/CU.
// U layout INTERLEAVED: col = dir*1024 + h*4 + k -> one 8B load per step.
// Depth-32 prefetch ring; exp2-based sigmoid, minimal loop-carried chain.
#define SCAN_PF 32
__global__ __launch_bounds__(64) void sru_scan(
    const __hip_bfloat16* __restrict__ U,
    const float* __restrict__ wc,    // (2,2,H): [dir][vf,vr][h]
    const float* __restrict__ bias,  // (2,2,H): [dir][bf,br][h]
    __hip_bfloat16* __restrict__ hout)
{
    const int id  = blockIdx.x * 64 + threadIdx.x;  // 0..16383
    const int dir = id >> 13;
    const int rem = id & 8191;
    const int b   = rem >> 8;
    const int h   = rem & 255;

    const float LOG2E = 1.44269504088896340736f;
    const float vf = wc[(dir * 2 + 0) * H_DIM + h];
    const float vr = wc[(dir * 2 + 1) * H_DIM + h];
    const float bf = bias[(dir * 2 + 0) * H_DIM + h];
    const float br = bias[(dir * 2 + 1) * H_DIM + h];
    const float nvf = -LOG2E * vf, nbf = -LOG2E * bf;
    const float nvr = -LOG2E * vr, nbr = -LOG2E * br;

    const long row0 = (long)b * T_DIM + (dir ? (T_DIM - 1) : 0);
    const uint2* p  = (const uint2*)(U + row0 * 2048 + dir * 1024 + (h << 2));
    const long pstep = dir ? -512 : 512;    // uint2 units

    __hip_bfloat16* ho = hout + row0 * 512 + dir * 256 + h;
    const long hstep = dir ? -512 : 512;

    uint2 buf[SCAN_PF];
#pragma unroll
    for (int j = 0; j < SCAN_PF; ++j) buf[j] = p[j * pstep];

    float c = 0.0f;
    for (int s0 = 0; s0 < T_DIM; s0 += SCAN_PF) {
#pragma unroll
        for (int j = 0; j < SCAN_PF; ++j) {
            const uint2 u = buf[j];
            const int sp = s0 + j + SCAN_PF;
            if (sp < T_DIM) buf[j] = p[(long)sp * pstep];
            float u0, u1, u2, u3;
            {
                unsigned a0 = u.x << 16, a1 = u.x & 0xffff0000u;
                unsigned a2 = u.y << 16, a3 = u.y & 0xffff0000u;
                __builtin_memcpy(&u0, &a0, 4); __builtin_memcpy(&u1, &a1, 4);
                __builtin_memcpy(&u2, &a2, 4); __builtin_memcpy(&u3, &a3, 4);
            }
            const float nf0 = __builtin_fmaf(-LOG2E, u1, nbf);
            const float nr0 = __builtin_fmaf(-LOG2E, u2, nbr);
            const float ef = __builtin_amdgcn_exp2f(__builtin_fmaf(nvf, c, nf0));
            const float er = __builtin_amdgcn_exp2f(__builtin_fmaf(nvr, c, nr0));
            const float f  = __builtin_amdgcn_rcpf(1.0f + ef);
            const float r  = __builtin_amdgcn_rcpf(1.0f + er);
            const float c2 = __builtin_fmaf(f, c - u0, u0);
            const float hv = __builtin_fmaf(r, c2 - u3, u3);
            c = c2;
            ho[(long)(s0 + j) * hstep] = __float2bfloat16(hv);
        }
    }
}

// ---------------------------------------------------------------------------
// MFMA logits + log_softmax. Block = 256 threads, 128 rows. K=256, N=32 (21
// used; lp_w zero-padded). B-tile LDS-resident (padded rows, conflict-free);
// A staged per 32-k chunk with the swizzled global_load_lds pattern.
__global__ __launch_bounds__(256) void logits_mfma(
    const __hip_bfloat16* __restrict__ fc,    // (M_ROWS,256) bf16
    const __hip_bfloat16* __restrict__ lpwb,  // (32,256) bf16, padded
    const float* __restrict__ lpb,            // (21,)
    float* __restrict__ out)
{
    // B: [0,16896) = 32 rows x 528B ; A stage: [16896,25088) = 8 x 1024B
    // C (f32) reuse: [0,18432) = 128 x 36 f32
    __shared__ __align__(16) char smb[25088];
    const int tid  = threadIdx.x;
    const int lane = tid & 63;
    const int wave = tid >> 6;
    const long m0  = (long)blockIdx.x * 128;

    // load lp weights into padded LDS (row stride 528 B)
    for (int idx = tid; idx < 32 * 32; idx += 256) {
        const int rw = idx >> 5, sl = idx & 31;
        *(bf16x8*)(smb + rw * 528 + sl * 16) =
            *(const bf16x8*)(lpwb + rw * 256 + sl * 8);
    }

    const int ldrow = lane >> 2;
    const int ldq   = lane & 3;
    const int gq    = ldq ^ ((ldrow >> 1) & 3);
    const int gkoff = gq * 8;

    const int fr = lane & 15;
    const int kq = lane >> 4;
    const int sw = (kq ^ ((fr >> 1) & 3)) * 16;

    f32x4 acc[2][2] = {};
    for (int kc = 0; kc < 8; ++kc) {
        __syncthreads();
#pragma unroll
        for (int i = 0; i < 2; ++i) {
            const int rc = wave * 2 + i;            // 0..7
            gload_lds16(fc + (m0 + rc * 16 + ldrow) * 256 + kc * 32 + gkoff,
                        smb + 16896 + rc * 1024);
        }
        __syncthreads();
        bf16x8 af[2], bfv[2];
#pragma unroll
        for (int i = 0; i < 2; ++i)
            af[i] = *(const bf16x8*)(smb + 16896 + (wave * 2 + i) * 1024 + fr * 64 + sw);
#pragma unroll
        for (int j = 0; j < 2; ++j)
            bfv[j] = *(const bf16x8*)(smb + (j * 16 + fr) * 528 + kc * 64 + kq * 16);
#pragma unroll
        for (int i = 0; i < 2; ++i)
#pragma unroll
            for (int j = 0; j < 2; ++j)
                acc[i][j] = __builtin_amdgcn_mfma_f32_16x16x32_bf16(
                    af[i], bfv[j], acc[i][j], 0, 0, 0);
    }

    __syncthreads();
    float* smC = (float*)smb;                  // stride 36 f32
    const int col_l = lane & 15;
    const int row_l = (lane >> 4) * 4;
#pragma unroll
    for (int j = 0; j < 2; ++j) {
        const int gc = j * 16 + col_l;
        const float bv = (gc < AA_DIM) ? lpb[gc] : 0.0f;
#pragma unroll
        for (int i = 0; i < 2; ++i)
#pragma unroll
            for (int r = 0; r < 4; ++r)
                smC[(wave * 32 + i * 16 + row_l + r) * 36 + gc] = acc[i][j][r] + bv;
    }
    __syncthreads();
    if (tid < 128) {
        const float* rowp = smC + tid * 36;
        float m = rowp[0];
#pragma unroll
        for (int a = 1; a < AA_DIM; ++a) m = fmaxf(m, rowp[a]);
        float s = 0.0f;
#pragma unroll
        for (int a = 0; a < AA_DIM; ++a) s += __expf(rowp[a] - m);
        const float lse = __logf(s) + m;
        float* op = out + (m0 + tid) * AA_DIM;
#pragma unroll
        for (int a = 0; a < AA_DIM; ++a) op[a] = rowp[a] - lse;
    }
}

// ---------------------------------------------------------------------------
extern "C" void kernel_launch(void* const* d_in, const int* in_sizes, int n_in,
                              void* d_out, int out_size, void* d_ws, size_t ws_size,
                              hipStream_t stream)
{
    const float* x     = (const float*)d_in[0];
    const float* w_l0  = (const float*)d_in[2];
    const float* wc_l0 = (const float*)d_in[3];
    const float* b_l0  = (const float*)d_in[4];
    const float* w_l1  = (const float*)d_in[5];
    const float* wc_l1 = (const float*)d_in[6];
    const float* b_l1  = (const float*)d_in[7];
    const float* fc1_w = (const float*)d_in[8];
    const float* fc1_b = (const float*)d_in[9];
    const float* lp_w  = (const float*)d_in[10];
    const float* lp_b  = (const float*)d_in[11];
    float* out = (float*)d_out;

    char* ws = (char*)d_ws;
    __hip_bfloat16* U      = (__hip_bfloat16*)(ws);              // 134,217,728 B
    __hip_bfloat16* h0b    = (__hip_bfloat16*)(ws + 134217728);  //  33,554,432
    __hip_bfloat16* h1b    = (__hip_bfloat16*)(ws + 167772160);  //  33,554,432
    __hip_bfloat16* xb     = (__hip_bfloat16*)(ws + 201326592);  //  16,777,216
    __hip_bfloat16* fcob   = xb;                                 //  alias after GEMM0
    __hip_bfloat16* w0t    = (__hip_bfloat16*)(ws + 218103808);  //  (2048,256)
    __hip_bfloat16* w1t    = (__hip_bfloat16*)(ws + 219152384);  //  (2048,512)
    __hip_bfloat16* fc1wb  = (__hip_bfloat16*)(ws + 221249536);  //  (256,512)
    __hip_bfloat16* lpwb   = (__hip_bfloat16*)(ws + 221511680);  //  (32,256)

    cvt_all<<<(CVT_TOT + 255) / 256, 256, 0, stream>>>(
        x, w_l0, w_l1, fc1_w, lp_w, xb, w0t, w1t, fc1wb, lpwb);

    // grid = MB*NB (1-D); MB=256, NB=16 -> 4096 blocks, nbShift=4
    gemm_bf16<<<4096, 256, 0, stream>>>(
        xb, w0t, nullptr, U, M_ROWS, 2048, DIN_DIM, 4);
    sru_scan<<<256, 64, 0, stream>>>(U, wc_l0, b_l0, h0b);
    gemm_bf16<<<4096, 256, 0, stream>>>(
        h0b, w1t, nullptr, U, M_ROWS, 2048, 512, 4);
    sru_scan<<<256, 64, 0, stream>>>(U, wc_l1, b_l1, h1b);
    // NB=2 -> 512 blocks, nbShift=1
    gemm_bf16<<<512, 256, 0, stream>>>(
        h1b, fc1wb, fc1_b, fcob, M_ROWS, 256, 512, 1);
    logits_mfma<<<M_ROWS / 128, 256, 0, stream>>>(fcob, lpwb, lp_b, out);
}

// Round 8
// 423.185 us; speedup vs baseline: 1.6809x; 1.1026x over previous
//
#include <hip/hip_runtime.h>
#include <hip/hip_bf16.h>

// Problem dims (fixed): T=1024, B=32, DIN=256, H=256, AA=21, L=2
#define T_DIM 1024
#define B_DIM 32
#define DIN_DIM 256
#define H_DIM 256
#define AA_DIM 21
#define M_ROWS (B_DIM * T_DIM)   // 32768 rows, row index = b*T + t everywhere

typedef __attribute__((ext_vector_type(8))) short bf16x8;   // 8 bf16 = 4 VGPRs
typedef __attribute__((ext_vector_type(4))) float f32x4;

typedef __attribute__((address_space(3))) void lds_void;
typedef const __attribute__((address_space(1))) void glb_void;

__device__ __forceinline__ void gload_lds16(const void* g, void* l) {
    // global gather (per-lane addr) -> LDS at (wave-uniform base + lane*16)
    __builtin_amdgcn_global_load_lds((glb_void*)g, (lds_void*)l, 16, 0, 0);
}

__device__ __forceinline__ float b2f(unsigned short v) {
    unsigned u = ((unsigned)v) << 16;
    float f;
    __builtin_memcpy(&f, &u, 4);
    return f;
}

__device__ __forceinline__ unsigned short f2bu(float f) {
    __hip_bfloat16 h = __float2bfloat16(f);
    unsigned short u;
    __builtin_memcpy(&u, &h, 2);
    return u;
}

// ---------------------------------------------------------------------------
// All weight/input converts fused into ONE dispatch (vectorized bulk paths).
// seg0: x (B,T,DIN) f32 -> xb bf16, float4 per thread
// seg1: w_l0 (256,2,4,256) -> w0t bf16 (2048,256), n = dir*1024 + h*4 + k
// seg2: w_l1 (512,2,4,256) -> w1t bf16 (2048,512), same interleave
// seg3: fc1_w (256,512)=(N,K) -> fc1wb bf16, float4 per thread
// seg4: lp_w (21,256) f32 -> lpwb bf16 (32,256), rows 21..31 zero
#define CVT_V0 2097152            // 8388608 / 4
#define CVT_N1 524288
#define CVT_N2 1048576
#define CVT_V3 32768              // 131072 / 4
#define CVT_N4 8192
#define CVT_TOT (CVT_V0 + CVT_N1 + CVT_N2 + CVT_V3 + CVT_N4)
__global__ __launch_bounds__(256) void cvt_all(
    const float* __restrict__ x,  const float* __restrict__ w0,
    const float* __restrict__ w1, const float* __restrict__ fcw,
    const float* __restrict__ lpw,
    __hip_bfloat16* __restrict__ xb,  __hip_bfloat16* __restrict__ w0t,
    __hip_bfloat16* __restrict__ w1t, __hip_bfloat16* __restrict__ fcwb,
    __hip_bfloat16* __restrict__ lpwb)
{
    int i = blockIdx.x * 256 + threadIdx.x;
    if (i < CVT_V0) {
        float4 v = ((const float4*)x)[i];
        ushort4 o = { f2bu(v.x), f2bu(v.y), f2bu(v.z), f2bu(v.w) };
        ((ushort4*)xb)[i] = o;
        return;
    }
    i -= CVT_V0;
    if (i < CVT_N1) {   // w0t, K=256; input flat ((kk*2+dir)*4+k)*H + h
        int kk = i >> 11, rem = i & 2047;
        int dir = rem >> 10, k = (rem >> 8) & 3, h = rem & 255;
        w0t[(long)(dir * 1024 + h * 4 + k) * 256 + kk] = __float2bfloat16(w0[i]);
        return;
    }
    i -= CVT_N1;
    if (i < CVT_N2) {   // w1t, K=512
        int kk = i >> 11, rem = i & 2047;
        int dir = rem >> 10, k = (rem >> 8) & 3, h = rem & 255;
        w1t[(long)(dir * 1024 + h * 4 + k) * 512 + kk] = __float2bfloat16(w1[i]);
        return;
    }
    i -= CVT_N2;
    if (i < CVT_V3) {
        float4 v = ((const float4*)fcw)[i];
        ushort4 o = { f2bu(v.x), f2bu(v.y), f2bu(v.z), f2bu(v.w) };
        ((ushort4*)fcwb)[i] = o;
        return;
    }
    i -= CVT_V3;
    if (i < CVT_N4) {   // lpwb (32,256), zero-padded past row 20
        int n = i >> 8, k = i & 255;
        lpwb[i] = __float2bfloat16(n < AA_DIM ? lpw[n * 256 + k] : 0.0f);
    }
}

// ---------------------------------------------------------------------------
// bf16 GEMM: C(M,N) = A(M,K) * Bt(N,K)^T  [+ bias], C stored bf16.
// 128x128 tile, BK=64. 1-D grid with XCD-aware swizzle (all NB n-blocks of an
// M-tile on ONE XCD -> L2-resident A-tile + B). Staging: row-major 16-row x
// 64B chunks with XOR k-quad swizzle -> conflict-free ds_read_b128 AND
// coalesced fetch. Epilogue: TWO 64-row LDS passes (16896 B, inside the 32 KB
// staging buffer -> LDS stays 32768 -> 5 blocks/CU), stride-132 padded tile
// (measured 0 conflicts), 16B/lane coalesced C stores.
__global__ __launch_bounds__(256) void gemm_bf16(
    const __hip_bfloat16* __restrict__ A,
    const __hip_bfloat16* __restrict__ Bt,
    const float* __restrict__ bias,   // len N or nullptr
    __hip_bfloat16* __restrict__ C,
    int M, int N, int K, int nbShift)
{
    __shared__ __align__(16) char smb[32768];

    const int tid  = threadIdx.x;
    const int lane = tid & 63;
    const int wave = tid >> 6;
    const int wm = wave & 1;
    const int wn = wave >> 1;

    const int L   = blockIdx.x;
    const int s   = L >> 3;
    const int nb  = s & ((1 << nbShift) - 1);
    const int mb  = ((s >> nbShift) << 3) + (L & 7);
    const long n0 = (long)nb * 128;
    const long m0 = (long)mb * 128;

    f32x4 acc[4][4] = {};

    // staging lane mapping
    const int ldrow = lane >> 2;                    // row within 16-row chunk
    const int ldq   = lane & 3;                     // LDS k-quad slot
    const int gq    = ldq ^ ((ldrow >> 1) & 3);     // global k-quad fetched
    const int gkoff = gq * 8;                       // elements

    // fragment read mapping
    const int fr = lane & 15;
    const int kq = lane >> 4;
    const int sw = (kq ^ ((fr >> 1) & 3)) * 16;     // swizzled slot byte offset

    for (int kb = 0; kb < K; kb += 64) {
        __syncthreads();
#pragma unroll
        for (int i = 0; i < 4; ++i) {
            const int cid = wave * 4 + i;       // 0..15
            const int rc  = cid >> 1;           // row-chunk 0..7
            const int kh  = cid & 1;            // k-half 0..1
            const long row = rc * 16 + ldrow;
            const int koff = kb + kh * 32 + gkoff;
            gload_lds16(A  + (m0 + row) * (long)K + koff,
                        smb + rc * 2048 + kh * 1024);
            gload_lds16(Bt + (n0 + row) * (long)K + koff,
                        smb + 16384 + rc * 2048 + kh * 1024);
        }
        __syncthreads();   // drains vmcnt(0): staged data visible

#pragma unroll
        for (int ss = 0; ss < 2; ++ss) {
            bf16x8 af[4], bfv[4];
#pragma unroll
            for (int i = 0; i < 4; ++i) {
                af[i]  = *(const bf16x8*)(smb + (wm * 4 + i) * 2048 + ss * 1024 + fr * 64 + sw);
                bfv[i] = *(const bf16x8*)(smb + 16384 + (wn * 4 + i) * 2048 + ss * 1024 + fr * 64 + sw);
            }
#pragma unroll
            for (int i = 0; i < 4; ++i)
#pragma unroll
                for (int j = 0; j < 4; ++j)
                    acc[i][j] = __builtin_amdgcn_mfma_f32_16x16x32_bf16(
                        af[i], bfv[j], acc[i][j], 0, 0, 0);
        }
    }

    // ---- epilogue: C/D layout col=lane&15, row=(lane>>4)*4+reg ----
    // Two 64-row passes through a [64][stride 132] bf16 LDS tile.
    const int col_l = lane & 15;
    const int row_l = (lane >> 4) * 4;
    __hip_bfloat16* smC = (__hip_bfloat16*)smb;   // stride 132 bf16 = 264 B
#pragma unroll
    for (int p = 0; p < 2; ++p) {
        __syncthreads();   // prior LDS reads (K-loop / previous pass) done
        if (wm == p) {     // waves p and p+2 hold rows p*64..p*64+63
#pragma unroll
            for (int j = 0; j < 4; ++j) {
                const long gc = n0 + wn * 64 + j * 16 + col_l;
                const float bv = bias ? bias[gc] : 0.0f;
#pragma unroll
                for (int i = 0; i < 4; ++i)
#pragma unroll
                    for (int r = 0; r < 4; ++r)
                        smC[(i * 16 + row_l + r) * 132 + wn * 64 + j * 16 + col_l] =
                            __float2bfloat16(acc[i][j][r] + bv);
            }
        }
        __syncthreads();
        // copy out 64 rows x 128 cols: 8 lanes/row x 32B/lane, coalesced
        const int cb = (tid & 7) * 16;      // col start (elems)
#pragma unroll
        for (int s2 = 0; s2 < 2; ++s2) {
            const int rr = s2 * 32 + (tid >> 3);
            const long gr = m0 + p * 64 + rr;
            bf16x8 v0 = *(const bf16x8*)(smC + rr * 132 + cb);
            bf16x8 v1 = *(const bf16x8*)(smC + rr * 132 + cb + 8);
            *(bf16x8*)(C + gr * (long)N + n0 + cb)     = v0;
            *(bf16x8*)(C + gr * (long)N + n0 + cb + 8) = v1;
        }
    }
}

// ---------------------------------------------------------------------------
// SRU scan, one thread per (dir, b, h) recurrence; 16384 threads = 1 wave/CU.
// U layout INTERLEAVED: col = dir*1024 + h*4 + k -> one 8B load per step.
// Depth-32 prefetch ring; exp2-based sigmoid, minimal loop-carried chain.
#define SCAN_PF 32
__global__ __launch_bounds__(64) void sru_scan(
    const __hip_bfloat16* __restrict__ U,
    const float* __restrict__ wc,    // (2,2,H): [dir][vf,vr][h]
    const float* __restrict__ bias,  // (2,2,H): [dir][bf,br][h]
    __hip_bfloat16* __restrict__ hout)
{
    const int id  = blockIdx.x * 64 + threadIdx.x;  // 0..16383
    const int dir = id >> 13;
    const int rem = id & 8191;
    const int b   = rem >> 8;
    const int h   = rem & 255;

    const float LOG2E = 1.44269504088896340736f;
    const float vf = wc[(dir * 2 + 0) * H_DIM + h];
    const float vr = wc[(dir * 2 + 1) * H_DIM + h];
    const float bf = bias[(dir * 2 + 0) * H_DIM + h];
    const float br = bias[(dir * 2 + 1) * H_DIM + h];
    const float nvf = -LOG2E * vf, nbf = -LOG2E * bf;
    const float nvr = -LOG2E * vr, nbr = -LOG2E * br;

    const long row0 = (long)b * T_DIM + (dir ? (T_DIM - 1) : 0);
    const uint2* p  = (const uint2*)(U + row0 * 2048 + dir * 1024 + (h << 2));
    const long pstep = dir ? -512 : 512;    // uint2 units

    __hip_bfloat16* ho = hout + row0 * 512 + dir * 256 + h;
    const long hstep = dir ? -512 : 512;

    uint2 buf[SCAN_PF];
#pragma unroll
    for (int j = 0; j < SCAN_PF; ++j) buf[j] = p[j * pstep];

    float c = 0.0f;
    for (int s0 = 0; s0 < T_DIM; s0 += SCAN_PF) {
#pragma unroll
        for (int j = 0; j < SCAN_PF; ++j) {
            const uint2 u = buf[j];
            const int sp = s0 + j + SCAN_PF;
            if (sp < T_DIM) buf[j] = p[(long)sp * pstep];
            float u0, u1, u2, u3;
            {
                unsigned a0 = u.x << 16, a1 = u.x & 0xffff0000u;
                unsigned a2 = u.y << 16, a3 = u.y & 0xffff0000u;
                __builtin_memcpy(&u0, &a0, 4); __builtin_memcpy(&u1, &a1, 4);
                __builtin_memcpy(&u2, &a2, 4); __builtin_memcpy(&u3, &a3, 4);
            }
            const float nf0 = __builtin_fmaf(-LOG2E, u1, nbf);
            const float nr0 = __builtin_fmaf(-LOG2E, u2, nbr);
            const float ef = __builtin_amdgcn_exp2f(__builtin_fmaf(nvf, c, nf0));
            const float er = __builtin_amdgcn_exp2f(__builtin_fmaf(nvr, c, nr0));
            const float f  = __builtin_amdgcn_rcpf(1.0f + ef);
            const float r  = __builtin_amdgcn_rcpf(1.0f + er);
            const float c2 = __builtin_fmaf(f, c - u0, u0);
            const float hv = __builtin_fmaf(r, c2 - u3, u3);
            c = c2;
            ho[(long)(s0 + j) * hstep] = __float2bfloat16(hv);
        }
    }
}

// ---------------------------------------------------------------------------
// MFMA logits + log_softmax. Block = 256 threads, 128 rows. K=256, N=32 (21
// used; lp_w zero-padded). B-tile LDS-resident (padded rows, conflict-free);
// A staged per 32-k chunk with the swizzled global_load_lds pattern.
__global__ __launch_bounds__(256) void logits_mfma(
    const __hip_bfloat16* __restrict__ fc,    // (M_ROWS,256) bf16
    const __hip_bfloat16* __restrict__ lpwb,  // (32,256) bf16, padded
    const float* __restrict__ lpb,            // (21,)
    float* __restrict__ out)
{
    // B: [0,16896) = 32 rows x 528B ; A stage: [16896,25088) = 8 x 1024B
    // C (f32) reuse: [0,18432) = 128 x 36 f32
    __shared__ __align__(16) char smb[25088];
    const int tid  = threadIdx.x;
    const int lane = tid & 63;
    const int wave = tid >> 6;
    const long m0  = (long)blockIdx.x * 128;

    for (int idx = tid; idx < 32 * 32; idx += 256) {
        const int rw = idx >> 5, sl = idx & 31;
        *(bf16x8*)(smb + rw * 528 + sl * 16) =
            *(const bf16x8*)(lpwb + rw * 256 + sl * 8);
    }

    const int ldrow = lane >> 2;
    const int ldq   = lane & 3;
    const int gq    = ldq ^ ((ldrow >> 1) & 3);
    const int gkoff = gq * 8;

    const int fr = lane & 15;
    const int kq = lane >> 4;
    const int sw = (kq ^ ((fr >> 1) & 3)) * 16;

    f32x4 acc[2][2] = {};
    for (int kc = 0; kc < 8; ++kc) {
        __syncthreads();
#pragma unroll
        for (int i = 0; i < 2; ++i) {
            const int rc = wave * 2 + i;            // 0..7
            gload_lds16(fc + (m0 + rc * 16 + ldrow) * 256 + kc * 32 + gkoff,
                        smb + 16896 + rc * 1024);
        }
        __syncthreads();
        bf16x8 af[2], bfv[2];
#pragma unroll
        for (int i = 0; i < 2; ++i)
            af[i] = *(const bf16x8*)(smb + 16896 + (wave * 2 + i) * 1024 + fr * 64 + sw);
#pragma unroll
        for (int j = 0; j < 2; ++j)
            bfv[j] = *(const bf16x8*)(smb + (j * 16 + fr) * 528 + kc * 64 + kq * 16);
#pragma unroll
        for (int i = 0; i < 2; ++i)
#pragma unroll
            for (int j = 0; j < 2; ++j)
                acc[i][j] = __builtin_amdgcn_mfma_f32_16x16x32_bf16(
                    af[i], bfv[j], acc[i][j], 0, 0, 0);
    }

    __syncthreads();
    float* smC = (float*)smb;                  // stride 36 f32
    const int col_l = lane & 15;
    const int row_l = (lane >> 4) * 4;
#pragma unroll
    for (int j = 0; j < 2; ++j) {
        const int gc = j * 16 + col_l;
        const float bv = (gc < AA_DIM) ? lpb[gc] : 0.0f;
#pragma unroll
        for (int i = 0; i < 2; ++i)
#pragma unroll
            for (int r = 0; r < 4; ++r)
                smC[(wave * 32 + i * 16 + row_l + r) * 36 + gc] = acc[i][j][r] + bv;
    }
    __syncthreads();
    if (tid < 128) {
        const float* rowp = smC + tid * 36;
        float m = rowp[0];
#pragma unroll
        for (int a = 1; a < AA_DIM; ++a) m = fmaxf(m, rowp[a]);
        float s = 0.0f;
#pragma unroll
        for (int a = 0; a < AA_DIM; ++a) s += __expf(rowp[a] - m);
        const float lse = __logf(s) + m;
        float* op = out + (m0 + tid) * AA_DIM;
#pragma unroll
        for (int a = 0; a < AA_DIM; ++a) op[a] = rowp[a] - lse;
    }
}

// ---------------------------------------------------------------------------
extern "C" void kernel_launch(void* const* d_in, const int* in_sizes, int n_in,
                              void* d_out, int out_size, void* d_ws, size_t ws_size,
                              hipStream_t stream)
{
    const float* x     = (const float*)d_in[0];
    const float* w_l0  = (const float*)d_in[2];
    const float* wc_l0 = (const float*)d_in[3];
    const float* b_l0  = (const float*)d_in[4];
    const float* w_l1  = (const float*)d_in[5];
    const float* wc_l1 = (const float*)d_in[6];
    const float* b_l1  = (const float*)d_in[7];
    const float* fc1_w = (const float*)d_in[8];
    const float* fc1_b = (const float*)d_in[9];
    const float* lp_w  = (const float*)d_in[10];
    const float* lp_b  = (const float*)d_in[11];
    float* out = (float*)d_out;

    char* ws = (char*)d_ws;
    __hip_bfloat16* U      = (__hip_bfloat16*)(ws);              // 134,217,728 B
    __hip_bfloat16* h0b    = (__hip_bfloat16*)(ws + 134217728);  //  33,554,432
    __hip_bfloat16* h1b    = (__hip_bfloat16*)(ws + 167772160);  //  33,554,432
    __hip_bfloat16* xb     = (__hip_bfloat16*)(ws + 201326592);  //  16,777,216
    __hip_bfloat16* fcob   = xb;                                 //  alias after GEMM0
    __hip_bfloat16* w0t    = (__hip_bfloat16*)(ws + 218103808);  //  (2048,256)
    __hip_bfloat16* w1t    = (__hip_bfloat16*)(ws + 219152384);  //  (2048,512)
    __hip_bfloat16* fc1wb  = (__hip_bfloat16*)(ws + 221249536);  //  (256,512)
    __hip_bfloat16* lpwb   = (__hip_bfloat16*)(ws + 221511680);  //  (32,256)

    cvt_all<<<(CVT_TOT + 255) / 256, 256, 0, stream>>>(
        x, w_l0, w_l1, fc1_w, lp_w, xb, w0t, w1t, fc1wb, lpwb);

    // grid = MB*NB (1-D); MB=256, NB=16 -> 4096 blocks, nbShift=4
    gemm_bf16<<<4096, 256, 0, stream>>>(
        xb, w0t, nullptr, U, M_ROWS, 2048, DIN_DIM, 4);
    sru_scan<<<256, 64, 0, stream>>>(U, wc_l0, b_l0, h0b);
    gemm_bf16<<<4096, 256, 0, stream>>>(
        h0b, w1t, nullptr, U, M_ROWS, 2048, 512, 4);
    sru_scan<<<256, 64, 0, stream>>>(U, wc_l1, b_l1, h1b);
    // NB=2 -> 512 blocks, nbShift=1
    gemm_bf16<<<512, 256, 0, stream>>>(
        h1b, fc1wb, fc1_b, fcob, M_ROWS, 256, 512, 1);
    logits_mfma<<<M_ROWS / 128, 256, 0, stream>>>(fcob, lpwb, lp_b, out);
}

// Round 9
// 419.685 us; speedup vs baseline: 1.6949x; 1.0083x over previous
//
#include <hip/hip_runtime.h>
#include <hip/hip_bf16.h>

// Problem dims (fixed): T=1024, B=32, DIN=256, H=256, AA=21, L=2
#define T_DIM 1024
#define B_DIM 32
#define DIN_DIM 256
#define H_DIM 256
#define AA_DIM 21
#define M_ROWS (B_DIM * T_DIM)   // 32768 rows, row index = b*T + t everywhere

typedef __attribute__((ext_vector_type(8))) short bf16x8;   // 8 bf16 = 4 VGPRs
typedef __attribute__((ext_vector_type(4))) float f32x4;

typedef __attribute__((address_space(3))) void lds_void;
typedef const __attribute__((address_space(1))) void glb_void;

#define LOG2E_F 1.44269504088896340736f

__device__ __forceinline__ void gload_lds16(const void* g, void* l) {
    // global gather (per-lane addr) -> LDS at (wave-uniform base + lane*16)
    __builtin_amdgcn_global_load_lds((glb_void*)g, (lds_void*)l, 16, 0, 0);
}

__device__ __forceinline__ float b2f(unsigned short v) {
    unsigned u = ((unsigned)v) << 16;
    float f;
    __builtin_memcpy(&f, &u, 4);
    return f;
}

__device__ __forceinline__ unsigned short f2bu(float f) {
    __hip_bfloat16 h = __float2bfloat16(f);
    unsigned short u;
    __builtin_memcpy(&u, &h, 2);
    return u;
}

// ---------------------------------------------------------------------------
// All weight/input converts fused into ONE dispatch (vectorized bulk paths).
// seg0: x (B,T,DIN) f32 -> xb bf16, float4 per thread
// seg1: w_l0 (256,2,4,256) -> w0t bf16 (2048,256), n = dir*1024 + h*4 + k
// seg2: w_l1 (512,2,4,256) -> w1t bf16 (2048,512), same interleave
// seg3: fc1_w (256,512)=(N,K) -> fc1wb bf16, float4 per thread
// seg4: lp_w (21,256) f32 -> lpwb bf16 (32,256), rows 21..31 zero
// seg5: per-column scale/bias vectors for the U GEMM epilogues:
//       gate k==1/2 columns get scale=-log2e, bias=-log2e*b[dir][k-1][h]
//       (scan's sigmoid arg is then exp2-ready without per-step fmas)
#define CVT_V0 2097152            // 8388608 / 4
#define CVT_N1 524288
#define CVT_N2 1048576
#define CVT_V3 32768              // 131072 / 4
#define CVT_N4 8192
#define CVT_N5 4096
#define CVT_TOT (CVT_V0 + CVT_N1 + CVT_N2 + CVT_V3 + CVT_N4 + CVT_N5)
__global__ __launch_bounds__(256) void cvt_all(
    const float* __restrict__ x,  const float* __restrict__ w0,
    const float* __restrict__ w1, const float* __restrict__ fcw,
    const float* __restrict__ lpw,
    const float* __restrict__ b0, const float* __restrict__ b1,
    __hip_bfloat16* __restrict__ xb,  __hip_bfloat16* __restrict__ w0t,
    __hip_bfloat16* __restrict__ w1t, __hip_bfloat16* __restrict__ fcwb,
    __hip_bfloat16* __restrict__ lpwb,
    float* __restrict__ sc0, float* __restrict__ bs0,
    float* __restrict__ sc1, float* __restrict__ bs1)
{
    int i = blockIdx.x * 256 + threadIdx.x;
    if (i < CVT_V0) {
        float4 v = ((const float4*)x)[i];
        ushort4 o = { f2bu(v.x), f2bu(v.y), f2bu(v.z), f2bu(v.w) };
        ((ushort4*)xb)[i] = o;
        return;
    }
    i -= CVT_V0;
    if (i < CVT_N1) {   // w0t, K=256; input flat ((kk*2+dir)*4+k)*H + h
        int kk = i >> 11, rem = i & 2047;
        int dir = rem >> 10, k = (rem >> 8) & 3, h = rem & 255;
        w0t[(long)(dir * 1024 + h * 4 + k) * 256 + kk] = __float2bfloat16(w0[i]);
        return;
    }
    i -= CVT_N1;
    if (i < CVT_N2) {   // w1t, K=512
        int kk = i >> 11, rem = i & 2047;
        int dir = rem >> 10, k = (rem >> 8) & 3, h = rem & 255;
        w1t[(long)(dir * 1024 + h * 4 + k) * 512 + kk] = __float2bfloat16(w1[i]);
        return;
    }
    i -= CVT_N2;
    if (i < CVT_V3) {
        float4 v = ((const float4*)fcw)[i];
        ushort4 o = { f2bu(v.x), f2bu(v.y), f2bu(v.z), f2bu(v.w) };
        ((ushort4*)fcwb)[i] = o;
        return;
    }
    i -= CVT_V3;
    if (i < CVT_N4) {   // lpwb (32,256), zero-padded past row 20
        int n = i >> 8, k = i & 255;
        lpwb[i] = __float2bfloat16(n < AA_DIM ? lpw[n * 256 + k] : 0.0f);
        return;
    }
    i -= CVT_N4;
    if (i < CVT_N5) {   // scale/bias vectors, 2048 per layer
        int layer = i >> 11, n = i & 2047;
        int k = n & 3, h = (n >> 2) & 255, dir = n >> 10;
        const float* bb = layer ? b1 : b0;
        float sc = 1.0f, bs = 0.0f;
        if (k == 1) { sc = -LOG2E_F; bs = -LOG2E_F * bb[(dir * 2 + 0) * 256 + h]; }
        if (k == 2) { sc = -LOG2E_F; bs = -LOG2E_F * bb[(dir * 2 + 1) * 256 + h]; }
        if (layer) { sc1[n] = sc; bs1[n] = bs; }
        else       { sc0[n] = sc; bs0[n] = bs; }
    }
}

// ---------------------------------------------------------------------------
// bf16 GEMM: C(M,N) = fma(A*Bt^T, scale_n, bias_n), C stored bf16.
// 128x128 tile, BK=64. 1-D grid with XCD-aware swizzle (all NB n-blocks of an
// M-tile on ONE XCD -> L2-resident A-tile + B). Staging: row-major 16-row x
// 64B chunks with XOR k-quad swizzle -> conflict-free ds_read_b128 AND
// coalesced fetch. Epilogue: TWO 64-row LDS passes (16896 B, inside the 32 KB
// staging buffer -> LDS stays 32768 -> 5 blocks/CU), stride-132 padded tile
// (measured 0 conflicts), 16B/lane coalesced C stores.
__global__ __launch_bounds__(256) void gemm_bf16(
    const __hip_bfloat16* __restrict__ A,
    const __hip_bfloat16* __restrict__ Bt,
    const float* __restrict__ bias,    // len N or nullptr
    const float* __restrict__ scale,   // len N or nullptr (1.0)
    __hip_bfloat16* __restrict__ C,
    int M, int N, int K, int nbShift)
{
    __shared__ __align__(16) char smb[32768];

    const int tid  = threadIdx.x;
    const int lane = tid & 63;
    const int wave = tid >> 6;
    const int wm = wave & 1;
    const int wn = wave >> 1;

    const int L   = blockIdx.x;
    const int s   = L >> 3;
    const int nb  = s & ((1 << nbShift) - 1);
    const int mb  = ((s >> nbShift) << 3) + (L & 7);
    const long n0 = (long)nb * 128;
    const long m0 = (long)mb * 128;

    f32x4 acc[4][4] = {};

    // staging lane mapping
    const int ldrow = lane >> 2;                    // row within 16-row chunk
    const int ldq   = lane & 3;                     // LDS k-quad slot
    const int gq    = ldq ^ ((ldrow >> 1) & 3);     // global k-quad fetched
    const int gkoff = gq * 8;                       // elements

    // fragment read mapping
    const int fr = lane & 15;
    const int kq = lane >> 4;
    const int sw = (kq ^ ((fr >> 1) & 3)) * 16;     // swizzled slot byte offset

    for (int kb = 0; kb < K; kb += 64) {
        __syncthreads();
#pragma unroll
        for (int i = 0; i < 4; ++i) {
            const int cid = wave * 4 + i;       // 0..15
            const int rc  = cid >> 1;           // row-chunk 0..7
            const int kh  = cid & 1;            // k-half 0..1
            const long row = rc * 16 + ldrow;
            const int koff = kb + kh * 32 + gkoff;
            gload_lds16(A  + (m0 + row) * (long)K + koff,
                        smb + rc * 2048 + kh * 1024);
            gload_lds16(Bt + (n0 + row) * (long)K + koff,
                        smb + 16384 + rc * 2048 + kh * 1024);
        }
        __syncthreads();   // drains vmcnt(0): staged data visible

#pragma unroll
        for (int ss = 0; ss < 2; ++ss) {
            bf16x8 af[4], bfv[4];
#pragma unroll
            for (int i = 0; i < 4; ++i) {
                af[i]  = *(const bf16x8*)(smb + (wm * 4 + i) * 2048 + ss * 1024 + fr * 64 + sw);
                bfv[i] = *(const bf16x8*)(smb + 16384 + (wn * 4 + i) * 2048 + ss * 1024 + fr * 64 + sw);
            }
#pragma unroll
            for (int i = 0; i < 4; ++i)
#pragma unroll
                for (int j = 0; j < 4; ++j)
                    acc[i][j] = __builtin_amdgcn_mfma_f32_16x16x32_bf16(
                        af[i], bfv[j], acc[i][j], 0, 0, 0);
        }
    }

    // ---- epilogue: C/D layout col=lane&15, row=(lane>>4)*4+reg ----
    // Two 64-row passes through a [64][stride 132] bf16 LDS tile.
    const int col_l = lane & 15;
    const int row_l = (lane >> 4) * 4;
    __hip_bfloat16* smC = (__hip_bfloat16*)smb;   // stride 132 bf16 = 264 B
#pragma unroll
    for (int p = 0; p < 2; ++p) {
        __syncthreads();   // prior LDS reads (K-loop / previous pass) done
        if (wm == p) {     // waves p and p+2 hold rows p*64..p*64+63
#pragma unroll
            for (int j = 0; j < 4; ++j) {
                const long gc = n0 + wn * 64 + j * 16 + col_l;
                const float bv = bias ? bias[gc] : 0.0f;
                const float av = scale ? scale[gc] : 1.0f;
#pragma unroll
                for (int i = 0; i < 4; ++i)
#pragma unroll
                    for (int r = 0; r < 4; ++r)
                        smC[(i * 16 + row_l + r) * 132 + wn * 64 + j * 16 + col_l] =
                            __float2bfloat16(__builtin_fmaf(acc[i][j][r], av, bv));
            }
        }
        __syncthreads();
        // copy out 64 rows x 128 cols: 8 lanes/row x 32B/lane, coalesced
        const int cb = (tid & 7) * 16;      // col start (elems)
#pragma unroll
        for (int s2 = 0; s2 < 2; ++s2) {
            const int rr = s2 * 32 + (tid >> 3);
            const long gr = m0 + p * 64 + rr;
            bf16x8 v0 = *(const bf16x8*)(smC + rr * 132 + cb);
            bf16x8 v1 = *(const bf16x8*)(smC + rr * 132 + cb + 8);
            *(bf16x8*)(C + gr * (long)N + n0 + cb)     = v0;
            *(bf16x8*)(C + gr * (long)N + n0 + cb + 8) = v1;
        }
    }
}

// ---------------------------------------------------------------------------
// SRU scan, one thread per (dir, b, h) recurrence; 16384 threads = 1 wave/CU.
// U layout INTERLEAVED (col = dir*1024 + h*4 + k), forget/reset columns
// pre-scaled to exp2-ready form in the GEMM epilogue. DIR is a template
// parameter -> compile-time strides, constant-offset unrolled loads/stores.
// Main loop prefetches unconditionally (legal while s0 < T-PF); tail has none.
#define SCAN_PF 32
template<int DIR>
__device__ __forceinline__ void scan_body(
    const __hip_bfloat16* __restrict__ U,
    const float* __restrict__ wc,
    __hip_bfloat16* __restrict__ hout, int id)
{
    const int rem = id & 8191;
    const int b   = rem >> 8;
    const int h   = rem & 255;

    const float nvf = -LOG2E_F * wc[(DIR * 2 + 0) * H_DIM + h];
    const float nvr = -LOG2E_F * wc[(DIR * 2 + 1) * H_DIM + h];

    const long row0 = (long)b * T_DIM + (DIR ? (T_DIM - 1) : 0);
    constexpr long PSTEP = DIR ? -512L : 512L;   // uint2 units (4 KB rows)
    constexpr long HSTEP = DIR ? -512L : 512L;   // bf16 units (1 KB rows)

    const uint2* __restrict__ p = (const uint2*)(U + row0 * 2048 + DIR * 1024 + (h << 2));
    __hip_bfloat16* __restrict__ hcur = hout + row0 * 512 + DIR * 256 + h;

    uint2 buf[SCAN_PF];
#pragma unroll
    for (int j = 0; j < SCAN_PF; ++j) buf[j] = p[(long)j * PSTEP];
    const uint2* __restrict__ pl = p + (long)SCAN_PF * PSTEP;

    float c = 0.0f;
    for (int s0 = 0; s0 < T_DIM - SCAN_PF; s0 += SCAN_PF) {
#pragma unroll
        for (int j = 0; j < SCAN_PF; ++j) {
            const uint2 u = buf[j];
            buf[j] = pl[(long)j * PSTEP];
            float u0, u1s, u2s, u3;
            {
                unsigned a0 = u.x << 16, a1 = u.x & 0xffff0000u;
                unsigned a2 = u.y << 16, a3 = u.y & 0xffff0000u;
                __builtin_memcpy(&u0, &a0, 4); __builtin_memcpy(&u1s, &a1, 4);
                __builtin_memcpy(&u2s, &a2, 4); __builtin_memcpy(&u3, &a3, 4);
            }
            const float ef = __builtin_amdgcn_exp2f(__builtin_fmaf(nvf, c, u1s));
            const float er = __builtin_amdgcn_exp2f(__builtin_fmaf(nvr, c, u2s));
            const float f  = __builtin_amdgcn_rcpf(1.0f + ef);
            const float r  = __builtin_amdgcn_rcpf(1.0f + er);
            const float c2 = __builtin_fmaf(f, c - u0, u0);
            const float hv = __builtin_fmaf(r, c2 - u3, u3);
            c = c2;
            hcur[(long)j * HSTEP] = __float2bfloat16(hv);
        }
        pl   += (long)SCAN_PF * PSTEP;
        hcur += (long)SCAN_PF * HSTEP;
    }
    // tail: last SCAN_PF steps, no prefetch
#pragma unroll
    for (int j = 0; j < SCAN_PF; ++j) {
        const uint2 u = buf[j];
        float u0, u1s, u2s, u3;
        {
            unsigned a0 = u.x << 16, a1 = u.x & 0xffff0000u;
            unsigned a2 = u.y << 16, a3 = u.y & 0xffff0000u;
            __builtin_memcpy(&u0, &a0, 4); __builtin_memcpy(&u1s, &a1, 4);
            __builtin_memcpy(&u2s, &a2, 4); __builtin_memcpy(&u3, &a3, 4);
        }
        const float ef = __builtin_amdgcn_exp2f(__builtin_fmaf(nvf, c, u1s));
        const float er = __builtin_amdgcn_exp2f(__builtin_fmaf(nvr, c, u2s));
        const float f  = __builtin_amdgcn_rcpf(1.0f + ef);
        const float r  = __builtin_amdgcn_rcpf(1.0f + er);
        const float c2 = __builtin_fmaf(f, c - u0, u0);
        const float hv = __builtin_fmaf(r, c2 - u3, u3);
        c = c2;
        hcur[(long)j * HSTEP] = __float2bfloat16(hv);
    }
}

__global__ __launch_bounds__(64) void sru_scan(
    const __hip_bfloat16* __restrict__ U,
    const float* __restrict__ wc,
    __hip_bfloat16* __restrict__ hout)
{
    const int id = blockIdx.x * 64 + threadIdx.x;  // 0..16383
    if (id < 8192) scan_body<0>(U, wc, hout, id);   // wave-uniform branch
    else           scan_body<1>(U, wc, hout, id);
}

// ---------------------------------------------------------------------------
// MFMA logits + log_softmax. Block = 256 threads, 128 rows. K=256, N=32 (21
// used; lp_w zero-padded). B-tile LDS-resident (padded rows, conflict-free);
// A staged per 32-k chunk with the swizzled global_load_lds pattern.
__global__ __launch_bounds__(256) void logits_mfma(
    const __hip_bfloat16* __restrict__ fc,    // (M_ROWS,256) bf16
    const __hip_bfloat16* __restrict__ lpwb,  // (32,256) bf16, padded
    const float* __restrict__ lpb,            // (21,)
    float* __restrict__ out)
{
    // B: [0,16896) = 32 rows x 528B ; A stage: [16896,25088) = 8 x 1024B
    // C (f32) reuse: [0,18432) = 128 x 36 f32
    __shared__ __align__(16) char smb[25088];
    const int tid  = threadIdx.x;
    const int lane = tid & 63;
    const int wave = tid >> 6;
    const long m0  = (long)blockIdx.x * 128;

    for (int idx = tid; idx < 32 * 32; idx += 256) {
        const int rw = idx >> 5, sl = idx & 31;
        *(bf16x8*)(smb + rw * 528 + sl * 16) =
            *(const bf16x8*)(lpwb + rw * 256 + sl * 8);
    }

    const int ldrow = lane >> 2;
    const int ldq   = lane & 3;
    const int gq    = ldq ^ ((ldrow >> 1) & 3);
    const int gkoff = gq * 8;

    const int fr = lane & 15;
    const int kq = lane >> 4;
    const int sw = (kq ^ ((fr >> 1) & 3)) * 16;

    f32x4 acc[2][2] = {};
    for (int kc = 0; kc < 8; ++kc) {
        __syncthreads();
#pragma unroll
        for (int i = 0; i < 2; ++i) {
            const int rc = wave * 2 + i;            // 0..7
            gload_lds16(fc + (m0 + rc * 16 + ldrow) * 256 + kc * 32 + gkoff,
                        smb + 16896 + rc * 1024);
        }
        __syncthreads();
        bf16x8 af[2], bfv[2];
#pragma unroll
        for (int i = 0; i < 2; ++i)
            af[i] = *(const bf16x8*)(smb + 16896 + (wave * 2 + i) * 1024 + fr * 64 + sw);
#pragma unroll
        for (int j = 0; j < 2; ++j)
            bfv[j] = *(const bf16x8*)(smb + (j * 16 + fr) * 528 + kc * 64 + kq * 16);
#pragma unroll
        for (int i = 0; i < 2; ++i)
#pragma unroll
            for (int j = 0; j < 2; ++j)
                acc[i][j] = __builtin_amdgcn_mfma_f32_16x16x32_bf16(
                    af[i], bfv[j], acc[i][j], 0, 0, 0);
    }

    __syncthreads();
    float* smC = (float*)smb;                  // stride 36 f32
    const int col_l = lane & 15;
    const int row_l = (lane >> 4) * 4;
#pragma unroll
    for (int j = 0; j < 2; ++j) {
        const int gc = j * 16 + col_l;
        const float bv = (gc < AA_DIM) ? lpb[gc] : 0.0f;
#pragma unroll
        for (int i = 0; i < 2; ++i)
#pragma unroll
            for (int r = 0; r < 4; ++r)
                smC[(wave * 32 + i * 16 + row_l + r) * 36 + gc] = acc[i][j][r] + bv;
    }
    __syncthreads();
    if (tid < 128) {
        const float* rowp = smC + tid * 36;
        float m = rowp[0];
#pragma unroll
        for (int a = 1; a < AA_DIM; ++a) m = fmaxf(m, rowp[a]);
        float s = 0.0f;
#pragma unroll
        for (int a = 0; a < AA_DIM; ++a) s += __expf(rowp[a] - m);
        const float lse = __logf(s) + m;
        float* op = out + (m0 + tid) * AA_DIM;
#pragma unroll
        for (int a = 0; a < AA_DIM; ++a) op[a] = rowp[a] - lse;
    }
}

// ---------------------------------------------------------------------------
extern "C" void kernel_launch(void* const* d_in, const int* in_sizes, int n_in,
                              void* d_out, int out_size, void* d_ws, size_t ws_size,
                              hipStream_t stream)
{
    const float* x     = (const float*)d_in[0];
    const float* w_l0  = (const float*)d_in[2];
    const float* wc_l0 = (const float*)d_in[3];
    const float* b_l0  = (const float*)d_in[4];
    const float* w_l1  = (const float*)d_in[5];
    const float* wc_l1 = (const float*)d_in[6];
    const float* b_l1  = (const float*)d_in[7];
    const float* fc1_w = (const float*)d_in[8];
    const float* fc1_b = (const float*)d_in[9];
    const float* lp_w  = (const float*)d_in[10];
    const float* lp_b  = (const float*)d_in[11];
    float* out = (float*)d_out;

    char* ws = (char*)d_ws;
    __hip_bfloat16* U      = (__hip_bfloat16*)(ws);              // 134,217,728 B
    __hip_bfloat16* h0b    = (__hip_bfloat16*)(ws + 134217728);  //  33,554,432
    __hip_bfloat16* h1b    = (__hip_bfloat16*)(ws + 167772160);  //  33,554,432
    __hip_bfloat16* xb     = (__hip_bfloat16*)(ws + 201326592);  //  16,777,216
    __hip_bfloat16* fcob   = xb;                                 //  alias after GEMM0
    __hip_bfloat16* w0t    = (__hip_bfloat16*)(ws + 218103808);  //  (2048,256)
    __hip_bfloat16* w1t    = (__hip_bfloat16*)(ws + 219152384);  //  (2048,512)
    __hip_bfloat16* fc1wb  = (__hip_bfloat16*)(ws + 221249536);  //  (256,512)
    __hip_bfloat16* lpwb   = (__hip_bfloat16*)(ws + 221511680);  //  (32,256)
    float* sc0 = (float*)(ws + 221528064);                       //  (2048,)
    float* bs0 = (float*)(ws + 221536256);                       //  (2048,)
    float* sc1 = (float*)(ws + 221544448);                       //  (2048,)
    float* bs1 = (float*)(ws + 221552640);                       //  (2048,)

    cvt_all<<<(CVT_TOT + 255) / 256, 256, 0, stream>>>(
        x, w_l0, w_l1, fc1_w, lp_w, b_l0, b_l1,
        xb, w0t, w1t, fc1wb, lpwb, sc0, bs0, sc1, bs1);

    // grid = MB*NB (1-D); MB=256, NB=16 -> 4096 blocks, nbShift=4
    gemm_bf16<<<4096, 256, 0, stream>>>(
        xb, w0t, bs0, sc0, U, M_ROWS, 2048, DIN_DIM, 4);
    sru_scan<<<256, 64, 0, stream>>>(U, wc_l0, h0b);
    gemm_bf16<<<4096, 256, 0, stream>>>(
        h0b, w1t, bs1, sc1, U, M_ROWS, 2048, 512, 4);
    sru_scan<<<256, 64, 0, stream>>>(U, wc_l1, h1b);
    // NB=2 -> 512 blocks, nbShift=1
    gemm_bf16<<<512, 256, 0, stream>>>(
        h1b, fc1wb, fc1_b, nullptr, fcob, M_ROWS, 256, 512, 1);
    logits_mfma<<<M_ROWS / 128, 256, 0, stream>>>(fcob, lpwb, lp_b, out);
}